// Round 1
// baseline (499.439 us; speedup 1.0000x reference)
//
#include <hip/hip_runtime.h>
#include <hip/hip_bf16.h>
#include <cmath>

// Problem constants: B=8 T=512 M=64 D=1024 H=16 DFF=4096, DH=64, ROT=32, L=576
using bf16 = __hip_bfloat16;
typedef __attribute__((ext_vector_type(8))) __bf16 bf16x8;
typedef __attribute__((ext_vector_type(4))) float f32x4;

struct __align__(8) bf16x4s { bf16 a, b, c, d; };

__device__ inline void gload_lds16(const void* g, void* l) {
  __builtin_amdgcn_global_load_lds(
      (__attribute__((address_space(1))) void*)g,
      (__attribute__((address_space(3))) void*)l, 16, 0, 0);
}

__device__ inline f32x4 mfma16(bf16x8 a, bf16x8 b, f32x4 c) {
  return __builtin_amdgcn_mfma_f32_16x16x32_bf16(a, b, c, 0, 0, 0);
}

// ---------------------------------------------------------------------------
// Generic C = A * B^T GEMM.  A: (M,K) bf16 row-major, B: (N,K) bf16 row-major.
// 128x128 tile, BK=64, 256 threads (4 waves, 2x2 of 64x64 per wave).
// MODE 0: bf16 out = acc + bias[c]
// MODE 1: f32  out = acc + bias[c] + resid[r*ldo+c]
// MODE 2: bf16 out = relu(acc + bias[c])^2
// MODE 3: f32  scores: out[z*512*576 + r*576 + c] = (c<=r+64)? acc*0.125 : -1e30
// MODE 4: bf16 attn-out scatter: out[b*512*1024 + r*1024 + h*64 + c], zg=zoff+z
// ---------------------------------------------------------------------------
template<int MODE>
__global__ __launch_bounds__(256) void gemm_bt(
    const bf16* __restrict__ A, int lda, long sA,
    const bf16* __restrict__ B, int ldb, long sB,
    const float* __restrict__ bias,
    const float* __restrict__ resid,
    void* __restrict__ Out,
    int M, int N, int K, int ldo, int zoff)
{
  __shared__ bf16 As[128 * 64];
  __shared__ bf16 Bs[128 * 64];
  const int tid = threadIdx.x;
  const int lane = tid & 63;
  const int wid = tid >> 6;
  const int wr = wid >> 1, wc = wid & 1;
  const int m0 = blockIdx.y * 128;
  const int n0 = blockIdx.x * 128;
  const int z = blockIdx.z;
  const bf16* Ab = A + (long)z * sA;
  const bf16* Bb = B + (long)z * sB;

  f32x4 acc[4][4] = {};

  for (int k0 = 0; k0 < K; k0 += 64) {
    // stage A and B tiles: 1024 chunks of 16B each, linear LDS layout
#pragma unroll
    for (int i = 0; i < 4; ++i) {
      int idx = i * 256 + tid;          // 0..1023
      int row = idx >> 3;               // 0..127
      int kc = (idx & 7) << 3;          // 0,8,..,56
      int ra = min(m0 + row, M - 1);    // clamp (never OOB read)
      gload_lds16(Ab + (long)ra * lda + (k0 + kc), As + idx * 8);
      int rb = min(n0 + row, N - 1);
      gload_lds16(Bb + (long)rb * ldb + (k0 + kc), Bs + idx * 8);
    }
    __syncthreads();   // compiler drains vmcnt before s_barrier
#pragma unroll
    for (int kk = 0; kk < 2; ++kk) {
      bf16x8 af[4], bq[4];
#pragma unroll
      for (int m = 0; m < 4; ++m)
        af[m] = *(const bf16x8*)&As[(wr * 64 + m * 16 + (lane & 15)) * 64 + kk * 32 + ((lane >> 4) << 3)];
#pragma unroll
      for (int n = 0; n < 4; ++n)
        bq[n] = *(const bf16x8*)&Bs[(wc * 64 + n * 16 + (lane & 15)) * 64 + kk * 32 + ((lane >> 4) << 3)];
#pragma unroll
      for (int m = 0; m < 4; ++m)
#pragma unroll
        for (int n = 0; n < 4; ++n)
          acc[m][n] = mfma16(af[m], bq[n], acc[m][n]);
    }
    __syncthreads();
  }

  // epilogue: C/D layout col=lane&15, row=(lane>>4)*4+j  [HW-verified m89/m91]
#pragma unroll
  for (int m = 0; m < 4; ++m) {
#pragma unroll
    for (int n = 0; n < 4; ++n) {
      int rbase = wr * 64 + m * 16 + ((lane >> 4) << 2);
      int c = n0 + wc * 64 + n * 16 + (lane & 15);
      if (c >= N) continue;
#pragma unroll
      for (int j = 0; j < 4; ++j) {
        int rr = m0 + rbase + j;
        if (rr >= M) continue;
        float v = acc[m][n][j];
        if constexpr (MODE == 0) {
          ((bf16*)Out)[(long)rr * ldo + c] = __float2bfloat16(v + bias[c]);
        } else if constexpr (MODE == 1) {
          ((float*)Out)[(long)rr * ldo + c] = v + bias[c] + resid[(long)rr * ldo + c];
        } else if constexpr (MODE == 2) {
          float t = v + bias[c];
          t = fmaxf(t, 0.0f);
          ((bf16*)Out)[(long)rr * ldo + c] = __float2bfloat16(t * t);
        } else if constexpr (MODE == 3) {
          float t = (c <= rr + 64) ? v * 0.125f : -1e30f;
          ((float*)Out)[(long)z * 294912 + (long)rr * 576 + c] = t;
        } else { // MODE 4
          int zg = zoff + z;
          int b = zg >> 4, hh = zg & 15;
          ((bf16*)Out)[(long)b * 524288 + (long)rr * 1024 + hh * 64 + c] = __float2bfloat16(v);
        }
      }
    }
  }
}

// ---------------------------------------------------------------------------
// LayerNorm over D=1024, one block per row. CONCAT: row from [memory|x].
// ---------------------------------------------------------------------------
template<bool CONCAT>
__global__ __launch_bounds__(256) void ln_kernel(
    const float* __restrict__ xin, const float* __restrict__ mem,
    const float* __restrict__ g, const float* __restrict__ beta,
    bf16* __restrict__ out)
{
  const int row = blockIdx.x;
  const float* src;
  if (CONCAT) {
    int b = row / 576, p = row % 576;
    src = (p < 64) ? (mem + ((long)b * 64 + p) * 1024)
                   : (xin + ((long)b * 512 + (p - 64)) * 1024);
  } else {
    src = xin + (long)row * 1024;
  }
  const int tid = threadIdx.x;
  float4 v = ((const float4*)src)[tid];
  float s = v.x + v.y + v.z + v.w;
  float s2 = v.x * v.x + v.y * v.y + v.z * v.z + v.w * v.w;
#pragma unroll
  for (int o = 32; o; o >>= 1) {
    s += __shfl_down(s, o);
    s2 += __shfl_down(s2, o);
  }
  __shared__ float red[8];
  const int w = tid >> 6, lane = tid & 63;
  if (lane == 0) { red[w] = s; red[4 + w] = s2; }
  __syncthreads();
  float S = red[0] + red[1] + red[2] + red[3];
  float S2 = red[4] + red[5] + red[6] + red[7];
  float mu = S * (1.0f / 1024.0f);
  float rs = rsqrtf(S2 * (1.0f / 1024.0f) - mu * mu + 1e-5f);
  float4 gg = ((const float4*)g)[tid];
  float4 bb = ((const float4*)beta)[tid];
  bf16x4s o4;
  o4.a = __float2bfloat16((v.x - mu) * rs * gg.x + bb.x);
  o4.b = __float2bfloat16((v.y - mu) * rs * gg.y + bb.y);
  o4.c = __float2bfloat16((v.z - mu) * rs * gg.z + bb.z);
  o4.d = __float2bfloat16((v.w - mu) * rs * gg.w + bb.w);
  *(bf16x4s*)(out + (long)row * 1024 + tid * 4) = o4;
}

// ---------------------------------------------------------------------------
// fp32 weights -> bf16, all 6 matrices packed [Wq|Wk|Wv|Wo|W1|W2]
// ---------------------------------------------------------------------------
__global__ __launch_bounds__(256) void cvt_weights(
    const float* __restrict__ wq, const float* __restrict__ wk,
    const float* __restrict__ wv, const float* __restrict__ wo,
    const float* __restrict__ w1, const float* __restrict__ w2,
    bf16* __restrict__ out)
{
  long e = ((long)blockIdx.x * 256 + threadIdx.x) * 4;
  const long DD = 1048576, DF = 4194304;
  const float* src; long base;
  if (e < DD)            { src = wq; base = 0; }
  else if (e < 2 * DD)   { src = wk; base = DD; }
  else if (e < 3 * DD)   { src = wv; base = 2 * DD; }
  else if (e < 4 * DD)   { src = wo; base = 3 * DD; }
  else if (e < 4 * DD + DF) { src = w1; base = 4 * DD; }
  else                   { src = w2; base = 4 * DD + DF; }
  float4 v = *(const float4*)(src + (e - base));
  bf16x4s o4;
  o4.a = __float2bfloat16(v.x);
  o4.b = __float2bfloat16(v.y);
  o4.c = __float2bfloat16(v.z);
  o4.d = __float2bfloat16(v.w);
  *(bf16x4s*)(out + e) = o4;
}

__global__ __launch_bounds__(256) void bias_concat(
    const float* __restrict__ bq, const float* __restrict__ bk,
    const float* __restrict__ bv, float* __restrict__ out)
{
  int i = blockIdx.x * 256 + threadIdx.x;
  if (i < 1024)      out[i] = bq[i];
  else if (i < 2048) out[i] = bk[i - 1024];
  else if (i < 3072) out[i] = bv[i - 2048];
}

// ---------------------------------------------------------------------------
// RoPE + head-layout reshape.
// qkv: (B*L, 3072) bf16 -> qh (B,H,T,64) [rows p>=64], kh (B,H,L,64),
// vt (B,H,64,L) [transposed for PV B^T GEMM].
// ---------------------------------------------------------------------------
__global__ __launch_bounds__(256) void rope_reshape(
    const bf16* __restrict__ qkv, bf16* __restrict__ qh,
    bf16* __restrict__ kh, bf16* __restrict__ vt)
{
  long i = (long)blockIdx.x * 256 + threadIdx.x;
  if (i >= 8L * 576 * 1024) return;
  int dfull = (int)(i & 1023);
  long bp = i >> 10;
  int p = (int)(bp % 576);
  int b = (int)(bp / 576);
  int h = dfull >> 6, d = dfull & 63;
  const bf16* rowp = qkv + bp * 3072;

  float cosv = 1.0f, sinv = 0.0f;
  const bool rot = d < 32;
  int pd = 0;
  if (rot) {
    int i0 = d & 15;
    // inv_freq = 10000^(-i0/16) = exp(-i0 * ln(10000)/16)
    float invf = expf(-(float)i0 * 0.5756462732485114f);
    float ang = (float)p * invf;
    cosv = cosf(ang); sinv = sinf(ang);
    pd = (d < 16) ? d + 16 : d - 16;
  }
  // K (+RoPE)
  {
    float v0 = __bfloat162float(rowp[1024 + dfull]);
    float ov = v0;
    if (rot) {
      float v1 = __bfloat162float(rowp[1024 + (h << 6) + pd]);
      ov = (d < 16) ? (v0 * cosv - v1 * sinv) : (v0 * cosv + v1 * sinv);
    }
    kh[(((long)b * 16 + h) * 576 + p) * 64 + d] = __float2bfloat16(ov);
  }
  // V transpose
  vt[(((long)b * 16 + h) * 64 + d) * 576 + p] = rowp[2048 + dfull];
  // Q (+RoPE), only the T query rows
  if (p >= 64) {
    float v0 = __bfloat162float(rowp[dfull]);
    float ov = v0;
    if (rot) {
      float v1 = __bfloat162float(rowp[(h << 6) + pd]);
      ov = (d < 16) ? (v0 * cosv - v1 * sinv) : (v0 * cosv + v1 * sinv);
    }
    qh[(((long)b * 16 + h) * 512 + (p - 64)) * 64 + d] = __float2bfloat16(ov);
  }
}

// ---------------------------------------------------------------------------
// Row softmax over 576 cols, one wave per row (9 elems/lane), fp32 -> bf16 P.
// ---------------------------------------------------------------------------
__global__ __launch_bounds__(256) void softmax_kernel(
    const float* __restrict__ S, bf16* __restrict__ P, int nrows)
{
  int row = blockIdx.x * 4 + (threadIdx.x >> 6);
  int lane = threadIdx.x & 63;
  if (row >= nrows) return;
  const float* s = S + (long)row * 576;
  float v[9];
  float mx = -1e30f;
#pragma unroll
  for (int j = 0; j < 9; ++j) { v[j] = s[lane + j * 64]; mx = fmaxf(mx, v[j]); }
#pragma unroll
  for (int o = 32; o; o >>= 1) mx = fmaxf(mx, __shfl_xor(mx, o));
  float sum = 0.0f;
#pragma unroll
  for (int j = 0; j < 9; ++j) { v[j] = expf(v[j] - mx); sum += v[j]; }
#pragma unroll
  for (int o = 32; o; o >>= 1) sum += __shfl_xor(sum, o);
  float inv = 1.0f / sum;
  bf16* p = P + (long)row * 576;
#pragma unroll
  for (int j = 0; j < 9; ++j) p[lane + j * 64] = __float2bfloat16(v[j] * inv);
}

// ---------------------------------------------------------------------------
extern "C" void kernel_launch(void* const* d_in, const int* in_sizes, int n_in,
                              void* d_out, int out_size, void* d_ws, size_t ws_size,
                              hipStream_t stream)
{
  (void)in_sizes; (void)n_in; (void)out_size;
  const float* x    = (const float*)d_in[0];
  const float* mem  = (const float*)d_in[1];
  const float* Wq   = (const float*)d_in[2];
  const float* bq   = (const float*)d_in[3];
  const float* Wk   = (const float*)d_in[4];
  const float* bk   = (const float*)d_in[5];
  const float* Wv   = (const float*)d_in[6];
  const float* bv   = (const float*)d_in[7];
  const float* Wo   = (const float*)d_in[8];
  const float* bo   = (const float*)d_in[9];
  const float* W1   = (const float*)d_in[10];
  const float* b1   = (const float*)d_in[11];
  const float* W2   = (const float*)d_in[12];
  const float* b2   = (const float*)d_in[13];
  const float* g_a  = (const float*)d_in[14];
  const float* bt_a = (const float*)d_in[15];
  const float* g_m  = (const float*)d_in[16];
  const float* bt_m = (const float*)d_in[17];
  float* out = (float*)d_out;

  char* ws = (char*)d_ws;
  size_t off = 0;
  auto carve = [&](size_t bytes) -> void* {
    void* p = ws + off;
    off = (off + bytes + 255) & ~(size_t)255;
    return p;
  };
  bf16*  wB   = (bf16*)carve(12582912L * 2);        // packed bf16 weights
  float* bqkv = (float*)carve(3072 * 4);
  bf16*  xa   = (bf16*)carve(4608L * 1024 * 2);     // LN1 out
  bf16*  qkv  = (bf16*)carve(4608L * 3072 * 2);     // QKV GEMM out
  bf16*  qh   = (bf16*)carve(8L * 16 * 512 * 64 * 2);
  bf16*  kh   = (bf16*)carve(8L * 16 * 576 * 64 * 2);
  bf16*  vt   = (bf16*)carve(8L * 16 * 576 * 64 * 2);
  bf16*  attn = (bf16*)carve(4096L * 1024 * 2);     // PV out, (B*T, D)
  float* x2   = (float*)carve(4096L * 1024 * 4);    // post-attn residual
  bf16*  xn   = (bf16*)carve(4096L * 1024 * 2);     // LN2 out
  bf16*  hbuf = (bf16*)carve(4096L * 4096 * 2);     // relu^2 hidden

  // chunk the 128 (b,h) attention batches so scores+P fit in remaining ws
  size_t remain = (ws_size > off) ? ws_size - off : 0;
  int CH = 128;
  while (CH > 1 && (size_t)CH * (512 * 576 * 6 + 512) > remain) CH >>= 1;
  float* sc = (float*)carve((size_t)CH * 512 * 576 * 4);
  bf16*  Pb = (bf16*)carve((size_t)CH * 512 * 576 * 2);

  cvt_weights<<<12288, 256, 0, stream>>>(Wq, Wk, Wv, Wo, W1, W2, wB);
  bias_concat<<<12, 256, 0, stream>>>(bq, bk, bv, bqkv);
  ln_kernel<true><<<4608, 256, 0, stream>>>(x, mem, g_a, bt_a, xa);

  // QKV: (4608,1024) x (3072,1024)^T -> (4608,3072)
  gemm_bt<0><<<dim3(24, 36, 1), 256, 0, stream>>>(
      xa, 1024, 0, wB, 1024, 0, bqkv, nullptr, qkv, 4608, 3072, 1024, 3072, 0);

  rope_reshape<<<18432, 256, 0, stream>>>(qkv, qh, kh, vt);

  for (int z0 = 0; z0 < 128; z0 += CH) {
    // scores: per (b,h): (512,64) x (576,64)^T -> (512,576), scale+mask
    gemm_bt<3><<<dim3(5, 4, CH), 256, 0, stream>>>(
        qh + (long)z0 * 32768, 64, 32768,
        kh + (long)z0 * 36864, 64, 36864,
        nullptr, nullptr, sc, 512, 576, 64, 576, z0);
    softmax_kernel<<<CH * 128, 256, 0, stream>>>(sc, Pb, CH * 512);
    // PV: per (b,h): (512,576) x (64,576)^T -> scatter into attn (B*T, D)
    gemm_bt<4><<<dim3(1, 4, CH), 256, 0, stream>>>(
        Pb, 576, 294912,
        vt + (long)z0 * 36864, 576, 36864,
        nullptr, nullptr, attn, 512, 64, 576, 1024, z0);
  }

  // Wo + residual(x): (4096,1024) x (1024,1024)^T + x -> x2 (fp32)
  gemm_bt<1><<<dim3(8, 32, 1), 256, 0, stream>>>(
      attn, 1024, 0, wB + 3145728L, 1024, 0, bo, x, x2, 4096, 1024, 1024, 1024, 0);

  ln_kernel<false><<<4096, 256, 0, stream>>>(x2, nullptr, g_m, bt_m, xn);

  // W1 + relu^2: (4096,1024) x (4096,1024)^T -> (4096,4096) bf16
  gemm_bt<2><<<dim3(32, 32, 1), 256, 0, stream>>>(
      xn, 1024, 0, wB + 4194304L, 1024, 0, b1, nullptr, hbuf, 4096, 4096, 1024, 4096, 0);

  // W2 + residual(x2): (4096,4096) x (1024,4096)^T + x2 -> d_out (fp32)
  gemm_bt<1><<<dim3(8, 32, 1), 256, 0, stream>>>(
      hbuf, 4096, 0, wB + 8388608L, 4096, 0, b2, x2, out, 4096, 1024, 4096, 1024, 0);
}

// Round 2
// 360.195 us; speedup vs baseline: 1.3866x; 1.3866x over previous
//
#include <hip/hip_runtime.h>
#include <hip/hip_bf16.h>
#include <cmath>

// Problem constants: B=8 T=512 M=64 D=1024 H=16 DFF=4096, DH=64, ROT=32, L=576
using bf16 = __hip_bfloat16;
typedef __attribute__((ext_vector_type(8))) __bf16 bf16x8;
typedef __attribute__((ext_vector_type(4))) float f32x4;

struct __align__(8) bf16x4s { bf16 a, b, c, d; };

__device__ inline void gload_lds16(const void* g, void* l) {
  __builtin_amdgcn_global_load_lds(
      (__attribute__((address_space(1))) void*)g,
      (__attribute__((address_space(3))) void*)l, 16, 0, 0);
}

__device__ inline f32x4 mfma16(bf16x8 a, bf16x8 b, f32x4 c) {
  return __builtin_amdgcn_mfma_f32_16x16x32_bf16(a, b, c, 0, 0, 0);
}

// ---------------------------------------------------------------------------
// C = A * B^T GEMM, 2-phase double-buffered (T3 minimum recipe).
// A: (M,K) bf16 row-major, B: (N,K) bf16 row-major.
// 128x128 tile, BK=64, 512 threads (8 waves, 4x2 grid of 32x64 per wave).
// MODE 0: bf16 out = acc + bias[c]
// MODE 1: f32  out = acc + bias[c] + resid[r*ldo+c]
// MODE 2: bf16 out = relu(acc + bias[c])^2
// ---------------------------------------------------------------------------
template<int MODE>
__global__ __launch_bounds__(512) void gemm_bt(
    const bf16* __restrict__ A, int lda,
    const bf16* __restrict__ B, int ldb,
    const float* __restrict__ bias,
    const float* __restrict__ resid,
    void* __restrict__ Out,
    int M, int N, int K, int ldo)
{
  __shared__ bf16 As[2][128 * 64];
  __shared__ bf16 Bs[2][128 * 64];   // 64 KiB total
  const int tid = threadIdx.x;
  const int lane = tid & 63;
  const int wid = tid >> 6;
  const int wr = wid >> 1, wc = wid & 1;    // 4x2 waves, 32x64 each
  const int m0 = blockIdx.y * 128;
  const int n0 = blockIdx.x * 128;

  f32x4 acc[2][4] = {};

  auto STAGE = [&](int buf, int k0) {
#pragma unroll
    for (int i = 0; i < 2; ++i) {
      int idx = i * 512 + tid;          // 0..1023
      int row = idx >> 3;               // 0..127
      int kc = (idx & 7) << 3;          // 0,8,..,56
      int ra = min(m0 + row, M - 1);
      gload_lds16(A + (long)ra * lda + (k0 + kc), &As[buf][idx * 8]);
      int rb = min(n0 + row, N - 1);
      gload_lds16(B + (long)rb * ldb + (k0 + kc), &Bs[buf][idx * 8]);
    }
  };

  const int nt = K >> 6;
  STAGE(0, 0);
  asm volatile("s_waitcnt vmcnt(0)" ::: "memory");
  __builtin_amdgcn_s_barrier();

  int cur = 0;
  for (int t = 0; t < nt; ++t) {
    if (t + 1 < nt) STAGE(cur ^ 1, (t + 1) << 6);
#pragma unroll
    for (int kk = 0; kk < 2; ++kk) {
      bf16x8 af[2], bq[4];
#pragma unroll
      for (int m = 0; m < 2; ++m)
        af[m] = *(const bf16x8*)&As[cur][(wr * 32 + m * 16 + (lane & 15)) * 64 + kk * 32 + ((lane >> 4) << 3)];
#pragma unroll
      for (int n = 0; n < 4; ++n)
        bq[n] = *(const bf16x8*)&Bs[cur][(wc * 64 + n * 16 + (lane & 15)) * 64 + kk * 32 + ((lane >> 4) << 3)];
#pragma unroll
      for (int m = 0; m < 2; ++m)
#pragma unroll
        for (int n = 0; n < 4; ++n)
          acc[m][n] = mfma16(af[m], bq[n], acc[m][n]);
    }
    if (t + 1 < nt) {
      asm volatile("s_waitcnt lgkmcnt(0)" ::: "memory");  // all ds_reads of cur done
      asm volatile("s_waitcnt vmcnt(0)" ::: "memory");    // next tile landed
      __builtin_amdgcn_s_barrier();
      cur ^= 1;
    }
  }

  // epilogue: C/D layout col=lane&15, row=(lane>>4)*4+j  [HW-verified m89/m91]
#pragma unroll
  for (int m = 0; m < 2; ++m) {
#pragma unroll
    for (int n = 0; n < 4; ++n) {
      int rbase = wr * 32 + m * 16 + ((lane >> 4) << 2);
      int c = n0 + wc * 64 + n * 16 + (lane & 15);
      if (c >= N) continue;
#pragma unroll
      for (int j = 0; j < 4; ++j) {
        int rr = m0 + rbase + j;
        if (rr >= M) continue;
        float v = acc[m][n][j];
        if constexpr (MODE == 0) {
          ((bf16*)Out)[(long)rr * ldo + c] = __float2bfloat16(v + bias[c]);
        } else if constexpr (MODE == 1) {
          ((float*)Out)[(long)rr * ldo + c] = v + bias[c] + resid[(long)rr * ldo + c];
        } else { // MODE 2
          float t2 = fmaxf(v + bias[c], 0.0f);
          ((bf16*)Out)[(long)rr * ldo + c] = __float2bfloat16(t2 * t2);
        }
      }
    }
  }
}

// ---------------------------------------------------------------------------
// Fused flash attention. One block per (q-tile of 128, (b,h)).
// qh pre-scaled by 0.125*log2e so softmax runs in exp2 domain.
// 256 threads = 4 waves; wave w owns q-rows [w*32, w*32+32).
// K tiles of 64 kv, double-buffered; V^T consumed from vt (B,H,64,576).
// ---------------------------------------------------------------------------
__global__ __launch_bounds__(256) void flash_attn(
    const bf16* __restrict__ qh, const bf16* __restrict__ kh,
    const bf16* __restrict__ vt, bf16* __restrict__ attn)
{
  __shared__ bf16 ks[2][64 * 64];    // K tile  [kv][d]
  __shared__ bf16 vs[2][64 * 64];    // V^T tile [d][kv]
  __shared__ bf16 pq[128 * 64];      // Q stage, then P (wave-private rows)
  const int tid = threadIdx.x, lane = tid & 63, wv = tid >> 6;
  const int qt = blockIdx.x, zh = blockIdx.y;
  const int b = zh >> 4, h = zh & 15;
  const int q0 = qt * 128;
  const bf16* qb = qh + (long)zh * 32768 + (long)q0 * 64;
  const bf16* kb = kh + (long)zh * 36864;
  const bf16* vb = vt + (long)zh * 36864;

  // stage Q tile (128x64)
#pragma unroll
  for (int i = 0; i < 4; ++i) {
    int idx = i * 256 + tid;
    gload_lds16(qb + (long)(idx >> 3) * 64 + ((idx & 7) << 3), pq + idx * 8);
  }
  auto stage_kv = [&](int bb, int j) {
#pragma unroll
    for (int it = 0; it < 2; ++it) {
      int idx = it * 256 + tid;   // K rows
      gload_lds16(kb + (long)(j * 64 + (idx >> 3)) * 64 + ((idx & 7) << 3), &ks[bb][idx * 8]);
    }
#pragma unroll
    for (int it = 0; it < 2; ++it) {
      int idx = it * 256 + tid;   // V^T rows (d)
      gload_lds16(vb + (long)(idx >> 3) * 576 + j * 64 + ((idx & 7) << 3), &vs[bb][idx * 8]);
    }
  };
  stage_kv(0, 0);
  asm volatile("s_waitcnt vmcnt(0)" ::: "memory");
  __builtin_amdgcn_s_barrier();

  // hoist Q fragments to registers (wave-private rows)
  bf16x8 qf[2][2];
#pragma unroll
  for (int m = 0; m < 2; ++m)
#pragma unroll
    for (int kk = 0; kk < 2; ++kk)
      qf[m][kk] = *(const bf16x8*)&pq[(wv * 32 + m * 16 + (lane & 15)) * 64 + kk * 32 + ((lane >> 4) << 3)];

  f32x4 acc_o[2][4] = {};
  float mrun[2][4], lrun[2][4];
#pragma unroll
  for (int m = 0; m < 2; ++m)
#pragma unroll
    for (int jj = 0; jj < 4; ++jj) { mrun[m][jj] = -1e30f; lrun[m][jj] = 0.0f; }

  const int nkv = qt * 2 + 3;   // max col needed = q0+191 -> q0/64+3 tiles
  int cur = 0;
  for (int j = 0; j < nkv; ++j) {
    if (j + 1 < nkv) stage_kv(cur ^ 1, j + 1);

    // S = Q K^T (already in log2 domain via Q pre-scale)
    f32x4 s[2][4] = {};
#pragma unroll
    for (int kk = 0; kk < 2; ++kk) {
      bf16x8 kf[4];
#pragma unroll
      for (int n = 0; n < 4; ++n)
        kf[n] = *(const bf16x8*)&ks[cur][(n * 16 + (lane & 15)) * 64 + kk * 32 + ((lane >> 4) << 3)];
#pragma unroll
      for (int m = 0; m < 2; ++m)
#pragma unroll
        for (int n = 0; n < 4; ++n)
          s[m][n] = mfma16(qf[m][kk], kf[n], s[m][n]);
    }
    // causal mask: allowed col <= q_global + 64
#pragma unroll
    for (int m = 0; m < 2; ++m)
#pragma unroll
      for (int n = 0; n < 4; ++n) {
        int c = j * 64 + n * 16 + (lane & 15);
#pragma unroll
        for (int jj = 0; jj < 4; ++jj) {
          int r = q0 + wv * 32 + m * 16 + ((lane >> 4) << 2) + jj;
          if (c > r + 64) s[m][n][jj] = -1e30f;
        }
      }
    // online softmax per row (row owned by 16-lane group)
#pragma unroll
    for (int m = 0; m < 2; ++m)
#pragma unroll
      for (int jj = 0; jj < 4; ++jj) {
        float pm = fmaxf(fmaxf(s[m][0][jj], s[m][1][jj]), fmaxf(s[m][2][jj], s[m][3][jj]));
#pragma unroll
        for (int off = 1; off < 16; off <<= 1) pm = fmaxf(pm, __shfl_xor(pm, off));
        float mnew = fmaxf(mrun[m][jj], pm);
        float sc = exp2f(mrun[m][jj] - mnew);
        mrun[m][jj] = mnew;
        float rs = 0.0f;
#pragma unroll
        for (int n = 0; n < 4; ++n) {
          float p = exp2f(s[m][n][jj] - mnew);
          s[m][n][jj] = p;
          rs += p;
        }
#pragma unroll
        for (int off = 1; off < 16; off <<= 1) rs += __shfl_xor(rs, off);
        lrun[m][jj] = lrun[m][jj] * sc + rs;
#pragma unroll
        for (int nd = 0; nd < 4; ++nd) acc_o[m][nd][jj] *= sc;
      }
    // P -> bf16 in wave-private LDS rows (C-layout -> A-layout transpose)
#pragma unroll
    for (int m = 0; m < 2; ++m)
#pragma unroll
      for (int n = 0; n < 4; ++n)
#pragma unroll
        for (int jj = 0; jj < 4; ++jj)
          pq[(wv * 32 + m * 16 + ((lane >> 4) << 2) + jj) * 64 + n * 16 + (lane & 15)] =
              __float2bfloat16(s[m][n][jj]);
    // O += P * V^T
#pragma unroll
    for (int kk = 0; kk < 2; ++kk) {
      bf16x8 pa[2], vf[4];
#pragma unroll
      for (int m = 0; m < 2; ++m)
        pa[m] = *(const bf16x8*)&pq[(wv * 32 + m * 16 + (lane & 15)) * 64 + kk * 32 + ((lane >> 4) << 3)];
#pragma unroll
      for (int nd = 0; nd < 4; ++nd)
        vf[nd] = *(const bf16x8*)&vs[cur][(nd * 16 + (lane & 15)) * 64 + kk * 32 + ((lane >> 4) << 3)];
#pragma unroll
      for (int m = 0; m < 2; ++m)
#pragma unroll
        for (int nd = 0; nd < 4; ++nd)
          acc_o[m][nd] = mfma16(pa[m], vf[nd], acc_o[m][nd]);
    }
    if (j + 1 < nkv) {
      asm volatile("s_waitcnt lgkmcnt(0)" ::: "memory");
      asm volatile("s_waitcnt vmcnt(0)" ::: "memory");
      __builtin_amdgcn_s_barrier();
      cur ^= 1;
    }
  }
  // epilogue: O / l, scatter into attn (B*T, D) at head column h*64
  bf16* ob = attn + ((long)b * 512 + q0) * 1024 + h * 64;
#pragma unroll
  for (int m = 0; m < 2; ++m)
#pragma unroll
    for (int jj = 0; jj < 4; ++jj) {
      float inv = 1.0f / lrun[m][jj];
      int r = wv * 32 + m * 16 + ((lane >> 4) << 2) + jj;
#pragma unroll
      for (int nd = 0; nd < 4; ++nd)
        ob[(long)r * 1024 + nd * 16 + (lane & 15)] = __float2bfloat16(acc_o[m][nd][jj] * inv);
    }
}

// ---------------------------------------------------------------------------
// LayerNorm over D=1024, one block per row. CONCAT: row from [memory|x].
// ---------------------------------------------------------------------------
template<bool CONCAT>
__global__ __launch_bounds__(256) void ln_kernel(
    const float* __restrict__ xin, const float* __restrict__ mem,
    const float* __restrict__ g, const float* __restrict__ beta,
    bf16* __restrict__ out)
{
  const int row = blockIdx.x;
  const float* src;
  if (CONCAT) {
    int b = row / 576, p = row % 576;
    src = (p < 64) ? (mem + ((long)b * 64 + p) * 1024)
                   : (xin + ((long)b * 512 + (p - 64)) * 1024);
  } else {
    src = xin + (long)row * 1024;
  }
  const int tid = threadIdx.x;
  float4 v = ((const float4*)src)[tid];
  float s = v.x + v.y + v.z + v.w;
  float s2 = v.x * v.x + v.y * v.y + v.z * v.z + v.w * v.w;
#pragma unroll
  for (int o = 32; o; o >>= 1) {
    s += __shfl_down(s, o);
    s2 += __shfl_down(s2, o);
  }
  __shared__ float red[8];
  const int w = tid >> 6, lane = tid & 63;
  if (lane == 0) { red[w] = s; red[4 + w] = s2; }
  __syncthreads();
  float S = red[0] + red[1] + red[2] + red[3];
  float S2 = red[4] + red[5] + red[6] + red[7];
  float mu = S * (1.0f / 1024.0f);
  float rs = rsqrtf(S2 * (1.0f / 1024.0f) - mu * mu + 1e-5f);
  float4 gg = ((const float4*)g)[tid];
  float4 bb = ((const float4*)beta)[tid];
  bf16x4s o4;
  o4.a = __float2bfloat16((v.x - mu) * rs * gg.x + bb.x);
  o4.b = __float2bfloat16((v.y - mu) * rs * gg.y + bb.y);
  o4.c = __float2bfloat16((v.z - mu) * rs * gg.z + bb.z);
  o4.d = __float2bfloat16((v.w - mu) * rs * gg.w + bb.w);
  *(bf16x4s*)(out + (long)row * 1024 + tid * 4) = o4;
}

// ---------------------------------------------------------------------------
// fp32 weights -> bf16, all 6 matrices packed [Wq|Wk|Wv|Wo|W1|W2]
// ---------------------------------------------------------------------------
__global__ __launch_bounds__(256) void cvt_weights(
    const float* __restrict__ wq, const float* __restrict__ wk,
    const float* __restrict__ wv, const float* __restrict__ wo,
    const float* __restrict__ w1, const float* __restrict__ w2,
    bf16* __restrict__ out)
{
  long e = ((long)blockIdx.x * 256 + threadIdx.x) * 4;
  const long DD = 1048576, DF = 4194304;
  const float* src; long base;
  if (e < DD)            { src = wq; base = 0; }
  else if (e < 2 * DD)   { src = wk; base = DD; }
  else if (e < 3 * DD)   { src = wv; base = 2 * DD; }
  else if (e < 4 * DD)   { src = wo; base = 3 * DD; }
  else if (e < 4 * DD + DF) { src = w1; base = 4 * DD; }
  else                   { src = w2; base = 4 * DD + DF; }
  float4 v = *(const float4*)(src + (e - base));
  bf16x4s o4;
  o4.a = __float2bfloat16(v.x);
  o4.b = __float2bfloat16(v.y);
  o4.c = __float2bfloat16(v.z);
  o4.d = __float2bfloat16(v.w);
  *(bf16x4s*)(out + e) = o4;
}

__global__ __launch_bounds__(256) void bias_concat(
    const float* __restrict__ bq, const float* __restrict__ bk,
    const float* __restrict__ bv, float* __restrict__ out)
{
  int i = blockIdx.x * 256 + threadIdx.x;
  if (i < 1024)      out[i] = bq[i];
  else if (i < 2048) out[i] = bk[i - 1024];
  else if (i < 3072) out[i] = bv[i - 2048];
}

// ---------------------------------------------------------------------------
// RoPE + head-layout reshape. Q is pre-scaled by 0.125*log2(e) so the fused
// attention computes softmax in the exp2 domain.
// qkv: (B*L, 3072) bf16 -> qh (B,H,T,64) [rows p>=64], kh (B,H,L,64),
// vt (B,H,64,L) [transposed for PV B^T MFMA].
// ---------------------------------------------------------------------------
__global__ __launch_bounds__(256) void rope_reshape(
    const bf16* __restrict__ qkv, bf16* __restrict__ qh,
    bf16* __restrict__ kh, bf16* __restrict__ vt)
{
  const float QSCALE = 0.18033688011112043f;  // 0.125 * log2(e)
  long i = (long)blockIdx.x * 256 + threadIdx.x;
  if (i >= 8L * 576 * 1024) return;
  int dfull = (int)(i & 1023);
  long bp = i >> 10;
  int p = (int)(bp % 576);
  int b = (int)(bp / 576);
  int h = dfull >> 6, d = dfull & 63;
  const bf16* rowp = qkv + bp * 3072;

  float cosv = 1.0f, sinv = 0.0f;
  const bool rot = d < 32;
  int pd = 0;
  if (rot) {
    int i0 = d & 15;
    float invf = expf(-(float)i0 * 0.5756462732485114f);  // 10000^(-i0/16)
    float ang = (float)p * invf;
    cosv = cosf(ang); sinv = sinf(ang);
    pd = (d < 16) ? d + 16 : d - 16;
  }
  // K (+RoPE)
  {
    float v0 = __bfloat162float(rowp[1024 + dfull]);
    float ov = v0;
    if (rot) {
      float v1 = __bfloat162float(rowp[1024 + (h << 6) + pd]);
      ov = (d < 16) ? (v0 * cosv - v1 * sinv) : (v0 * cosv + v1 * sinv);
    }
    kh[(((long)b * 16 + h) * 576 + p) * 64 + d] = __float2bfloat16(ov);
  }
  // V transpose
  vt[(((long)b * 16 + h) * 64 + d) * 576 + p] = rowp[2048 + dfull];
  // Q (+RoPE, + scale), only the T query rows
  if (p >= 64) {
    float v0 = __bfloat162float(rowp[dfull]);
    float ov = v0;
    if (rot) {
      float v1 = __bfloat162float(rowp[(h << 6) + pd]);
      ov = (d < 16) ? (v0 * cosv - v1 * sinv) : (v0 * cosv + v1 * sinv);
    }
    qh[(((long)b * 16 + h) * 512 + (p - 64)) * 64 + d] = __float2bfloat16(ov * QSCALE);
  }
}

// ---------------------------------------------------------------------------
extern "C" void kernel_launch(void* const* d_in, const int* in_sizes, int n_in,
                              void* d_out, int out_size, void* d_ws, size_t ws_size,
                              hipStream_t stream)
{
  (void)in_sizes; (void)n_in; (void)out_size; (void)ws_size;
  const float* x    = (const float*)d_in[0];
  const float* mem  = (const float*)d_in[1];
  const float* Wq   = (const float*)d_in[2];
  const float* bq   = (const float*)d_in[3];
  const float* Wk   = (const float*)d_in[4];
  const float* bk   = (const float*)d_in[5];
  const float* Wv   = (const float*)d_in[6];
  const float* bv   = (const float*)d_in[7];
  const float* Wo   = (const float*)d_in[8];
  const float* bo   = (const float*)d_in[9];
  const float* W1   = (const float*)d_in[10];
  const float* b1   = (const float*)d_in[11];
  const float* W2   = (const float*)d_in[12];
  const float* b2   = (const float*)d_in[13];
  const float* g_a  = (const float*)d_in[14];
  const float* bt_a = (const float*)d_in[15];
  const float* g_m  = (const float*)d_in[16];
  const float* bt_m = (const float*)d_in[17];
  float* out = (float*)d_out;

  char* ws = (char*)d_ws;
  size_t off = 0;
  auto carve = [&](size_t bytes) -> void* {
    void* p = ws + off;
    off = (off + bytes + 255) & ~(size_t)255;
    return p;
  };
  bf16*  wB   = (bf16*)carve(12582912L * 2);        // packed bf16 weights
  float* bqkv = (float*)carve(3072 * 4);
  bf16*  xa   = (bf16*)carve(4608L * 1024 * 2);     // LN1 out
  bf16*  qkv  = (bf16*)carve(4608L * 3072 * 2);     // QKV GEMM out
  bf16*  qh   = (bf16*)carve(8L * 16 * 512 * 64 * 2);
  bf16*  kh   = (bf16*)carve(8L * 16 * 576 * 64 * 2);
  bf16*  vt   = (bf16*)carve(8L * 16 * 576 * 64 * 2);
  bf16*  attn = (bf16*)carve(4096L * 1024 * 2);     // flash out, (B*T, D)
  float* x2   = (float*)carve(4096L * 1024 * 4);    // post-attn residual
  bf16*  xn   = (bf16*)carve(4096L * 1024 * 2);     // LN2 out
  bf16*  hbuf = (bf16*)carve(4096L * 4096 * 2);     // relu^2 hidden

  cvt_weights<<<12288, 256, 0, stream>>>(Wq, Wk, Wv, Wo, W1, W2, wB);
  bias_concat<<<12, 256, 0, stream>>>(bq, bk, bv, bqkv);
  ln_kernel<true><<<4608, 256, 0, stream>>>(x, mem, g_a, bt_a, xa);

  // QKV: (4608,1024) x (3072,1024)^T -> (4608,3072)
  gemm_bt<0><<<dim3(24, 36), 512, 0, stream>>>(
      xa, 1024, wB, 1024, bqkv, nullptr, qkv, 4608, 3072, 1024, 3072);

  rope_reshape<<<18432, 256, 0, stream>>>(qkv, qh, kh, vt);

  // fused flash attention: grid (q-tile, b*h)
  flash_attn<<<dim3(4, 128), 256, 0, stream>>>(qh, kh, vt, attn);

  // Wo + residual(x): (4096,1024) x (1024,1024)^T + x -> x2 (fp32)
  gemm_bt<1><<<dim3(8, 32), 512, 0, stream>>>(
      attn, 1024, wB + 3145728L, 1024, bo, x, x2, 4096, 1024, 1024, 1024);

  ln_kernel<false><<<4096, 256, 0, stream>>>(x2, nullptr, g_m, bt_m, xn);

  // W1 + relu^2: (4096,1024) x (4096,1024)^T -> (4096,4096) bf16
  gemm_bt<2><<<dim3(32, 32), 512, 0, stream>>>(
      xn, 1024, wB + 4194304L, 1024, b1, nullptr, hbuf, 4096, 4096, 1024, 4096);

  // W2 + residual(x2): (4096,4096) x (1024,4096)^T + x2 -> d_out (fp32)
  gemm_bt<1><<<dim3(8, 32), 512, 0, stream>>>(
      hbuf, 4096, wB + 8388608L, 4096, b2, x2, out, 4096, 1024, 4096, 1024);
}

// Round 3
// 357.069 us; speedup vs baseline: 1.3987x; 1.0088x over previous
//
#include <hip/hip_runtime.h>
#include <hip/hip_bf16.h>
#include <cmath>

// Problem constants: B=8 T=512 M=64 D=1024 H=16 DFF=4096, DH=64, ROT=32, L=576
using bf16 = __hip_bfloat16;
typedef __attribute__((ext_vector_type(8))) __bf16 bf16x8;
typedef __attribute__((ext_vector_type(4))) float f32x4;

struct __align__(8) bf16x4s { bf16 a, b, c, d; };

__device__ inline void gload_lds16(const void* g, void* l) {
  __builtin_amdgcn_global_load_lds(
      (__attribute__((address_space(1))) void*)g,
      (__attribute__((address_space(3))) void*)l, 16, 0, 0);
}

__device__ inline f32x4 mfma16(bf16x8 a, bf16x8 b, f32x4 c) {
  return __builtin_amdgcn_mfma_f32_16x16x32_bf16(a, b, c, 0, 0, 0);
}

// ---------------------------------------------------------------------------
// C = A * B^T GEMM, m97 structure: 128x128 tile, BK=64, 256 threads (4 waves,
// 2x2 of 64x64 per wave), single-buffered 32 KiB LDS, global_load_lds width 16.
// blockIdx.z = split-K slice (A,B column offset z*sA/z*sB elements).
// MODE 0: bf16 out = acc + bias[c]
// MODE 2: bf16 out = relu(acc + bias[c])^2
// MODE 5: fp32 partial: Out[z*M*ldo + r*ldo + c] = acc
// ---------------------------------------------------------------------------
template<int MODE>
__global__ __launch_bounds__(256) void gemm_bt(
    const bf16* __restrict__ A, int lda, long sA,
    const bf16* __restrict__ B, int ldb, long sB,
    const float* __restrict__ bias,
    void* __restrict__ Out,
    int M, int N, int K, int ldo)
{
  __shared__ bf16 As[128 * 64];
  __shared__ bf16 Bs[128 * 64];
  const int tid = threadIdx.x;
  const int lane = tid & 63;
  const int wid = tid >> 6;
  const int wr = wid >> 1, wc = wid & 1;    // 2x2 waves, 64x64 each
  const int m0 = blockIdx.y * 128;
  const int n0 = blockIdx.x * 128;
  const int z = blockIdx.z;
  const bf16* Ab = A + (long)z * sA;
  const bf16* Bb = B + (long)z * sB;

  f32x4 acc[4][4] = {};

  for (int k0 = 0; k0 < K; k0 += 64) {
#pragma unroll
    for (int i = 0; i < 4; ++i) {
      int idx = i * 256 + tid;          // 0..1023
      int row = idx >> 3;               // 0..127
      int kc = (idx & 7) << 3;          // 0,8,..,56
      int ra = min(m0 + row, M - 1);
      gload_lds16(Ab + (long)ra * lda + (k0 + kc), As + idx * 8);
      int rb = min(n0 + row, N - 1);
      gload_lds16(Bb + (long)rb * ldb + (k0 + kc), Bs + idx * 8);
    }
    __syncthreads();
#pragma unroll
    for (int kk = 0; kk < 2; ++kk) {
      bf16x8 af[4], bq[4];
#pragma unroll
      for (int m = 0; m < 4; ++m)
        af[m] = *(const bf16x8*)&As[(wr * 64 + m * 16 + (lane & 15)) * 64 + kk * 32 + ((lane >> 4) << 3)];
#pragma unroll
      for (int n = 0; n < 4; ++n)
        bq[n] = *(const bf16x8*)&Bs[(wc * 64 + n * 16 + (lane & 15)) * 64 + kk * 32 + ((lane >> 4) << 3)];
#pragma unroll
      for (int m = 0; m < 4; ++m)
#pragma unroll
        for (int n = 0; n < 4; ++n)
          acc[m][n] = mfma16(af[m], bq[n], acc[m][n]);
    }
    __syncthreads();
  }

  // epilogue: C/D layout col=lane&15, row=(lane>>4)*4+j  [HW-verified m89/m91]
#pragma unroll
  for (int m = 0; m < 4; ++m) {
#pragma unroll
    for (int n = 0; n < 4; ++n) {
      int rbase = wr * 64 + m * 16 + ((lane >> 4) << 2);
      int c = n0 + wc * 64 + n * 16 + (lane & 15);
      if (c >= N) continue;
#pragma unroll
      for (int j = 0; j < 4; ++j) {
        int rr = m0 + rbase + j;
        if (rr >= M) continue;
        float v = acc[m][n][j];
        if constexpr (MODE == 0) {
          ((bf16*)Out)[(long)rr * ldo + c] = __float2bfloat16(v + bias[c]);
        } else if constexpr (MODE == 2) {
          float t2 = fmaxf(v + bias[c], 0.0f);
          ((bf16*)Out)[(long)rr * ldo + c] = __float2bfloat16(t2 * t2);
        } else { // MODE 5: fp32 partial
          ((float*)Out)[(long)z * M * ldo + (long)rr * ldo + c] = v;
        }
      }
    }
  }
}

// ---------------------------------------------------------------------------
// Split-K reduce: out = sum_z part[z] + bias + resid   (all fp32, float4)
// ---------------------------------------------------------------------------
template<int SK>
__global__ __launch_bounds__(256) void reduce_k(
    const float* __restrict__ part, const float* __restrict__ bias,
    const float* __restrict__ resid, float* __restrict__ out,
    int ldo4, long total4)
{
  long i = (long)blockIdx.x * 256 + threadIdx.x;
  if (i >= total4) return;
  const float4* p4 = (const float4*)part;
  float4 s = p4[i];
#pragma unroll
  for (int z = 1; z < SK; ++z) {
    float4 t = p4[(long)z * total4 + i];
    s.x += t.x; s.y += t.y; s.z += t.z; s.w += t.w;
  }
  float4 b = ((const float4*)bias)[(int)(i % ldo4)];
  float4 r = ((const float4*)resid)[i];
  s.x += b.x + r.x; s.y += b.y + r.y; s.z += b.z + r.z; s.w += b.w + r.w;
  ((float4*)out)[i] = s;
}

// ---------------------------------------------------------------------------
// Fused flash attention. One block per (q-tile of 128, (b,h)).
// qh pre-scaled by 0.125*log2e so softmax runs in exp2 domain.
// 256 threads = 4 waves; wave w owns q-rows [w*32, w*32+32).
// K tiles of 64 kv, double-buffered; V^T consumed from vt (B,H,64,576).
// ---------------------------------------------------------------------------
__global__ __launch_bounds__(256) void flash_attn(
    const bf16* __restrict__ qh, const bf16* __restrict__ kh,
    const bf16* __restrict__ vt, bf16* __restrict__ attn)
{
  __shared__ bf16 ks[2][64 * 64];    // K tile  [kv][d]
  __shared__ bf16 vs[2][64 * 64];    // V^T tile [d][kv]
  __shared__ bf16 pq[128 * 64];      // Q stage, then P (wave-private rows)
  const int tid = threadIdx.x, lane = tid & 63, wv = tid >> 6;
  const int qt = blockIdx.x, zh = blockIdx.y;
  const int b = zh >> 4, h = zh & 15;
  const int q0 = qt * 128;
  const bf16* qb = qh + (long)zh * 32768 + (long)q0 * 64;
  const bf16* kb = kh + (long)zh * 36864;
  const bf16* vb = vt + (long)zh * 36864;

  // stage Q tile (128x64)
#pragma unroll
  for (int i = 0; i < 4; ++i) {
    int idx = i * 256 + tid;
    gload_lds16(qb + (long)(idx >> 3) * 64 + ((idx & 7) << 3), pq + idx * 8);
  }
  auto stage_kv = [&](int bb, int j) {
#pragma unroll
    for (int it = 0; it < 2; ++it) {
      int idx = it * 256 + tid;   // K rows
      gload_lds16(kb + (long)(j * 64 + (idx >> 3)) * 64 + ((idx & 7) << 3), &ks[bb][idx * 8]);
    }
#pragma unroll
    for (int it = 0; it < 2; ++it) {
      int idx = it * 256 + tid;   // V^T rows (d)
      gload_lds16(vb + (long)(idx >> 3) * 576 + j * 64 + ((idx & 7) << 3), &vs[bb][idx * 8]);
    }
  };
  stage_kv(0, 0);
  asm volatile("s_waitcnt vmcnt(0)" ::: "memory");
  __builtin_amdgcn_s_barrier();

  // hoist Q fragments to registers (wave-private rows)
  bf16x8 qf[2][2];
#pragma unroll
  for (int m = 0; m < 2; ++m)
#pragma unroll
    for (int kk = 0; kk < 2; ++kk)
      qf[m][kk] = *(const bf16x8*)&pq[(wv * 32 + m * 16 + (lane & 15)) * 64 + kk * 32 + ((lane >> 4) << 3)];

  f32x4 acc_o[2][4] = {};
  float mrun[2][4], lrun[2][4];
#pragma unroll
  for (int m = 0; m < 2; ++m)
#pragma unroll
    for (int jj = 0; jj < 4; ++jj) { mrun[m][jj] = -1e30f; lrun[m][jj] = 0.0f; }

  const int nkv = qt * 2 + 3;   // max col needed = q0+191 -> q0/64+3 tiles
  int cur = 0;
  for (int j = 0; j < nkv; ++j) {
    if (j + 1 < nkv) stage_kv(cur ^ 1, j + 1);

    // S = Q K^T (already in log2 domain via Q pre-scale)
    f32x4 s[2][4] = {};
#pragma unroll
    for (int kk = 0; kk < 2; ++kk) {
      bf16x8 kf[4];
#pragma unroll
      for (int n = 0; n < 4; ++n)
        kf[n] = *(const bf16x8*)&ks[cur][(n * 16 + (lane & 15)) * 64 + kk * 32 + ((lane >> 4) << 3)];
#pragma unroll
      for (int m = 0; m < 2; ++m)
#pragma unroll
        for (int n = 0; n < 4; ++n)
          s[m][n] = mfma16(qf[m][kk], kf[n], s[m][n]);
    }
    // causal mask: allowed col <= q_global + 64
#pragma unroll
    for (int m = 0; m < 2; ++m)
#pragma unroll
      for (int n = 0; n < 4; ++n) {
        int c = j * 64 + n * 16 + (lane & 15);
#pragma unroll
        for (int jj = 0; jj < 4; ++jj) {
          int r = q0 + wv * 32 + m * 16 + ((lane >> 4) << 2) + jj;
          if (c > r + 64) s[m][n][jj] = -1e30f;
        }
      }
    // online softmax per row (row owned by 16-lane group)
#pragma unroll
    for (int m = 0; m < 2; ++m)
#pragma unroll
      for (int jj = 0; jj < 4; ++jj) {
        float pm = fmaxf(fmaxf(s[m][0][jj], s[m][1][jj]), fmaxf(s[m][2][jj], s[m][3][jj]));
#pragma unroll
        for (int off = 1; off < 16; off <<= 1) pm = fmaxf(pm, __shfl_xor(pm, off));
        float mnew = fmaxf(mrun[m][jj], pm);
        float sc = exp2f(mrun[m][jj] - mnew);
        mrun[m][jj] = mnew;
        float rs = 0.0f;
#pragma unroll
        for (int n = 0; n < 4; ++n) {
          float p = exp2f(s[m][n][jj] - mnew);
          s[m][n][jj] = p;
          rs += p;
        }
#pragma unroll
        for (int off = 1; off < 16; off <<= 1) rs += __shfl_xor(rs, off);
        lrun[m][jj] = lrun[m][jj] * sc + rs;
#pragma unroll
        for (int nd = 0; nd < 4; ++nd) acc_o[m][nd][jj] *= sc;
      }
    // P -> bf16 in wave-private LDS rows (C-layout -> A-layout transpose)
#pragma unroll
    for (int m = 0; m < 2; ++m)
#pragma unroll
      for (int n = 0; n < 4; ++n)
#pragma unroll
        for (int jj = 0; jj < 4; ++jj)
          pq[(wv * 32 + m * 16 + ((lane >> 4) << 2) + jj) * 64 + n * 16 + (lane & 15)] =
              __float2bfloat16(s[m][n][jj]);
    // O += P * V^T
#pragma unroll
    for (int kk = 0; kk < 2; ++kk) {
      bf16x8 pa[2], vf[4];
#pragma unroll
      for (int m = 0; m < 2; ++m)
        pa[m] = *(const bf16x8*)&pq[(wv * 32 + m * 16 + (lane & 15)) * 64 + kk * 32 + ((lane >> 4) << 3)];
#pragma unroll
      for (int nd = 0; nd < 4; ++nd)
        vf[nd] = *(const bf16x8*)&vs[cur][(nd * 16 + (lane & 15)) * 64 + kk * 32 + ((lane >> 4) << 3)];
#pragma unroll
      for (int m = 0; m < 2; ++m)
#pragma unroll
        for (int nd = 0; nd < 4; ++nd)
          acc_o[m][nd] = mfma16(pa[m], vf[nd], acc_o[m][nd]);
    }
    if (j + 1 < nkv) {
      asm volatile("s_waitcnt lgkmcnt(0)" ::: "memory");
      asm volatile("s_waitcnt vmcnt(0)" ::: "memory");
      __builtin_amdgcn_s_barrier();
      cur ^= 1;
    }
  }
  // epilogue: O / l, scatter into attn (B*T, D) at head column h*64
  bf16* ob = attn + ((long)b * 512 + q0) * 1024 + h * 64;
#pragma unroll
  for (int m = 0; m < 2; ++m)
#pragma unroll
    for (int jj = 0; jj < 4; ++jj) {
      float inv = 1.0f / lrun[m][jj];
      int r = wv * 32 + m * 16 + ((lane >> 4) << 2) + jj;
#pragma unroll
      for (int nd = 0; nd < 4; ++nd)
        ob[(long)r * 1024 + nd * 16 + (lane & 15)] = __float2bfloat16(acc_o[m][nd][jj] * inv);
    }
}

// ---------------------------------------------------------------------------
// LayerNorm over D=1024, one block per row. CONCAT: row from [memory|x].
// ---------------------------------------------------------------------------
template<bool CONCAT>
__global__ __launch_bounds__(256) void ln_kernel(
    const float* __restrict__ xin, const float* __restrict__ mem,
    const float* __restrict__ g, const float* __restrict__ beta,
    bf16* __restrict__ out)
{
  const int row = blockIdx.x;
  const float* src;
  if (CONCAT) {
    int b = row / 576, p = row % 576;
    src = (p < 64) ? (mem + ((long)b * 64 + p) * 1024)
                   : (xin + ((long)b * 512 + (p - 64)) * 1024);
  } else {
    src = xin + (long)row * 1024;
  }
  const int tid = threadIdx.x;
  float4 v = ((const float4*)src)[tid];
  float s = v.x + v.y + v.z + v.w;
  float s2 = v.x * v.x + v.y * v.y + v.z * v.z + v.w * v.w;
#pragma unroll
  for (int o = 32; o; o >>= 1) {
    s += __shfl_down(s, o);
    s2 += __shfl_down(s2, o);
  }
  __shared__ float red[8];
  const int w = tid >> 6, lane = tid & 63;
  if (lane == 0) { red[w] = s; red[4 + w] = s2; }
  __syncthreads();
  float S = red[0] + red[1] + red[2] + red[3];
  float S2 = red[4] + red[5] + red[6] + red[7];
  float mu = S * (1.0f / 1024.0f);
  float rs = rsqrtf(S2 * (1.0f / 1024.0f) - mu * mu + 1e-5f);
  float4 gg = ((const float4*)g)[tid];
  float4 bb = ((const float4*)beta)[tid];
  bf16x4s o4;
  o4.a = __float2bfloat16((v.x - mu) * rs * gg.x + bb.x);
  o4.b = __float2bfloat16((v.y - mu) * rs * gg.y + bb.y);
  o4.c = __float2bfloat16((v.z - mu) * rs * gg.z + bb.z);
  o4.d = __float2bfloat16((v.w - mu) * rs * gg.w + bb.w);
  *(bf16x4s*)(out + (long)row * 1024 + tid * 4) = o4;
}

// ---------------------------------------------------------------------------
// fp32 weights -> bf16, all 6 matrices packed [Wq|Wk|Wv|Wo|W1|W2]
// ---------------------------------------------------------------------------
__global__ __launch_bounds__(256) void cvt_weights(
    const float* __restrict__ wq, const float* __restrict__ wk,
    const float* __restrict__ wv, const float* __restrict__ wo,
    const float* __restrict__ w1, const float* __restrict__ w2,
    bf16* __restrict__ out)
{
  long e = ((long)blockIdx.x * 256 + threadIdx.x) * 4;
  const long DD = 1048576, DF = 4194304;
  const float* src; long base;
  if (e < DD)            { src = wq; base = 0; }
  else if (e < 2 * DD)   { src = wk; base = DD; }
  else if (e < 3 * DD)   { src = wv; base = 2 * DD; }
  else if (e < 4 * DD)   { src = wo; base = 3 * DD; }
  else if (e < 4 * DD + DF) { src = w1; base = 4 * DD; }
  else                   { src = w2; base = 4 * DD + DF; }
  float4 v = *(const float4*)(src + (e - base));
  bf16x4s o4;
  o4.a = __float2bfloat16(v.x);
  o4.b = __float2bfloat16(v.y);
  o4.c = __float2bfloat16(v.z);
  o4.d = __float2bfloat16(v.w);
  *(bf16x4s*)(out + e) = o4;
}

__global__ __launch_bounds__(256) void bias_concat(
    const float* __restrict__ bq, const float* __restrict__ bk,
    const float* __restrict__ bv, float* __restrict__ out)
{
  int i = blockIdx.x * 256 + threadIdx.x;
  if (i < 1024)      out[i] = bq[i];
  else if (i < 2048) out[i] = bk[i - 1024];
  else if (i < 3072) out[i] = bv[i - 2048];
}

// cos/sin table for RoPE: tab[p*16+f] = cos(p * 10000^(-f/16)), +9216 for sin
__global__ __launch_bounds__(256) void rope_tab_kernel(float* __restrict__ tab)
{
  int i = blockIdx.x * 256 + threadIdx.x;
  if (i >= 9216) return;
  int p = i >> 4, f = i & 15;
  float invf = expf(-(float)f * 0.5756462732485114f);  // 10000^(-f/16)
  float ang = (float)p * invf;
  tab[i] = cosf(ang);
  tab[9216 + i] = sinf(ang);
}

// ---------------------------------------------------------------------------
// RoPE + head-layout reshape. Q is pre-scaled by 0.125*log2(e) so the fused
// attention computes softmax in the exp2 domain.
// qkv: (B*L, 3072) bf16 -> qh (B,H,T,64) [rows p>=64], kh (B,H,L,64),
// vt (B,H,64,L) [transposed for PV B^T MFMA].
// ---------------------------------------------------------------------------
__global__ __launch_bounds__(256) void rope_reshape(
    const bf16* __restrict__ qkv, const float* __restrict__ tab,
    bf16* __restrict__ qh, bf16* __restrict__ kh, bf16* __restrict__ vt)
{
  const float QSCALE = 0.18033688011112043f;  // 0.125 * log2(e)
  long i = (long)blockIdx.x * 256 + threadIdx.x;
  if (i >= 8L * 576 * 1024) return;
  int dfull = (int)(i & 1023);
  long bp = i >> 10;
  int p = (int)(bp % 576);
  int b = (int)(bp / 576);
  int h = dfull >> 6, d = dfull & 63;
  const bf16* rowp = qkv + bp * 3072;

  float cosv = 1.0f, sinv = 0.0f;
  const bool rot = d < 32;
  int pd = 0;
  if (rot) {
    int i0 = d & 15;
    cosv = tab[p * 16 + i0];
    sinv = tab[9216 + p * 16 + i0];
    pd = (d < 16) ? d + 16 : d - 16;
  }
  // K (+RoPE)
  {
    float v0 = __bfloat162float(rowp[1024 + dfull]);
    float ov = v0;
    if (rot) {
      float v1 = __bfloat162float(rowp[1024 + (h << 6) + pd]);
      ov = (d < 16) ? (v0 * cosv - v1 * sinv) : (v0 * cosv + v1 * sinv);
    }
    kh[(((long)b * 16 + h) * 576 + p) * 64 + d] = __float2bfloat16(ov);
  }
  // V transpose
  vt[(((long)b * 16 + h) * 64 + d) * 576 + p] = rowp[2048 + dfull];
  // Q (+RoPE, + scale), only the T query rows
  if (p >= 64) {
    float v0 = __bfloat162float(rowp[dfull]);
    float ov = v0;
    if (rot) {
      float v1 = __bfloat162float(rowp[(h << 6) + pd]);
      ov = (d < 16) ? (v0 * cosv - v1 * sinv) : (v0 * cosv + v1 * sinv);
    }
    qh[(((long)b * 16 + h) * 512 + (p - 64)) * 64 + d] = __float2bfloat16(ov * QSCALE);
  }
}

// ---------------------------------------------------------------------------
extern "C" void kernel_launch(void* const* d_in, const int* in_sizes, int n_in,
                              void* d_out, int out_size, void* d_ws, size_t ws_size,
                              hipStream_t stream)
{
  (void)in_sizes; (void)n_in; (void)out_size; (void)ws_size;
  const float* x    = (const float*)d_in[0];
  const float* mem  = (const float*)d_in[1];
  const float* Wq   = (const float*)d_in[2];
  const float* bq   = (const float*)d_in[3];
  const float* Wk   = (const float*)d_in[4];
  const float* bk   = (const float*)d_in[5];
  const float* Wv   = (const float*)d_in[6];
  const float* bv   = (const float*)d_in[7];
  const float* Wo   = (const float*)d_in[8];
  const float* bo   = (const float*)d_in[9];
  const float* W1   = (const float*)d_in[10];
  const float* b1   = (const float*)d_in[11];
  const float* W2   = (const float*)d_in[12];
  const float* b2   = (const float*)d_in[13];
  const float* g_a  = (const float*)d_in[14];
  const float* bt_a = (const float*)d_in[15];
  const float* g_m  = (const float*)d_in[16];
  const float* bt_m = (const float*)d_in[17];
  float* out = (float*)d_out;

  char* ws = (char*)d_ws;
  size_t off = 0;
  auto carve = [&](size_t bytes) -> void* {
    void* p = ws + off;
    off = (off + bytes + 255) & ~(size_t)255;
    return p;
  };
  bf16*  wB    = (bf16*)carve(12582912L * 2);        // packed bf16 weights
  float* bqkv  = (float*)carve(3072 * 4);
  float* rtab  = (float*)carve(9216 * 2 * 4);        // rope cos/sin table
  bf16*  xa    = (bf16*)carve(4608L * 1024 * 2);     // LN1 out
  bf16*  qkv   = (bf16*)carve(4608L * 3072 * 2);     // QKV GEMM out
  bf16*  qh    = (bf16*)carve(8L * 16 * 512 * 64 * 2);
  bf16*  kh    = (bf16*)carve(8L * 16 * 576 * 64 * 2);
  bf16*  vt    = (bf16*)carve(8L * 16 * 576 * 64 * 2);
  bf16*  attn  = (bf16*)carve(4096L * 1024 * 2);     // flash out, (B*T, D)
  float* x2    = (float*)carve(4096L * 1024 * 4);    // post-attn residual
  bf16*  xn    = (bf16*)carve(4096L * 1024 * 2);     // LN2 out
  bf16*  hbuf  = (bf16*)carve(4096L * 4096 * 2);     // relu^2 hidden
  float* parts = (float*)carve(4L * 4096 * 1024 * 4);// split-K partials (67MB)

  cvt_weights<<<12288, 256, 0, stream>>>(Wq, Wk, Wv, Wo, W1, W2, wB);
  bias_concat<<<12, 256, 0, stream>>>(bq, bk, bv, bqkv);
  rope_tab_kernel<<<36, 256, 0, stream>>>(rtab);
  ln_kernel<true><<<4608, 256, 0, stream>>>(x, mem, g_a, bt_a, xa);

  // QKV: (4608,1024) x (3072,1024)^T -> (4608,3072)   grid 864 = 3.4 blk/CU
  gemm_bt<0><<<dim3(24, 36, 1), 256, 0, stream>>>(
      xa, 1024, 0, wB, 1024, 0, bqkv, qkv, 4608, 3072, 1024, 3072);

  rope_reshape<<<18432, 256, 0, stream>>>(qkv, rtab, qh, kh, vt);

  // fused flash attention: grid (q-tile, b*h)
  flash_attn<<<dim3(4, 128), 256, 0, stream>>>(qh, kh, vt, attn);

  // Wo split-K=2: (4096,1024) x (1024,1024)^T, each slice K=512 -> 512 blocks
  gemm_bt<5><<<dim3(8, 32, 2), 256, 0, stream>>>(
      attn, 1024, 512, wB + 3145728L, 1024, 512, nullptr, parts, 4096, 1024, 512, 1024);
  // x2 = sum(parts) + bo + x
  reduce_k<2><<<4096, 256, 0, stream>>>(parts, bo, x, x2, 256, 1048576);

  ln_kernel<false><<<4096, 256, 0, stream>>>(x2, nullptr, g_m, bt_m, xn);

  // W1 + relu^2: (4096,1024) x (4096,1024)^T -> (4096,4096) bf16  grid 1024
  gemm_bt<2><<<dim3(32, 32, 1), 256, 0, stream>>>(
      xn, 1024, 0, wB + 4194304L, 1024, 0, b1, hbuf, 4096, 4096, 1024, 4096);

  // W2 split-K=4: (4096,4096) x (1024,4096)^T, each slice K=1024 -> 1024 blocks
  gemm_bt<5><<<dim3(8, 32, 4), 256, 0, stream>>>(
      hbuf, 4096, 1024, wB + 8388608L, 4096, 1024, nullptr, parts, 4096, 1024, 1024, 1024);
  // out = sum(parts) + b2 + x2
  reduce_k<4><<<4096, 256, 0, stream>>>(parts, b2, x2, out, 256, 1048576);
}

// Round 4
// 274.315 us; speedup vs baseline: 1.8207x; 1.3017x over previous
//
#include <hip/hip_runtime.h>
#include <hip/hip_bf16.h>
#include <cmath>

// Problem constants: B=8 T=512 M=64 D=1024 H=16 DFF=4096, DH=64, ROT=32, L=576
using bf16 = __hip_bfloat16;
typedef __attribute__((ext_vector_type(8))) __bf16 bf16x8;
typedef __attribute__((ext_vector_type(4))) float f32x4;

struct __align__(8) bf16x4s { bf16 a, b, c, d; };

__device__ inline void gload_lds16(const void* g, void* l) {
  __builtin_amdgcn_global_load_lds(
      (__attribute__((address_space(1))) void*)g,
      (__attribute__((address_space(3))) void*)l, 16, 0, 0);
}

__device__ inline f32x4 mfma16(bf16x8 a, bf16x8 b, f32x4 c) {
  return __builtin_amdgcn_mfma_f32_16x16x32_bf16(a, b, c, 0, 0, 0);
}

#define BAR() __builtin_amdgcn_s_barrier()
#define VMC(N) asm volatile("s_waitcnt vmcnt(" #N ")" ::: "memory")

// ---------------------------------------------------------------------------
// C = A * B^T, 256x256 tile, BK=64, 512 threads (8 waves, 2x4; per-wave
// 128x64 output). 8-phase schedule, counted vmcnt(4) at phases 4/8 only.
// LDS: 8 half-slots x 16KB (2-tile ring): [par*4 + {A0,A1,B0,B1}].
// XOR swizzle byte^=((row&7)<<4): linear gload_lds dest + pre-swizzled global
// source; ds_reads apply the same XOR -> conflict-free b128 fragment reads.
// blockIdx.z = split-K slice (A,B k-offset z*sA / z*sB elements).
// MODE 0: bf16 out = acc + bias[c]
// MODE 2: bf16 out = relu(acc + bias[c])^2
// MODE 5: fp32 partial: Out[z*zstride + r*ldo + c] = acc
// ---------------------------------------------------------------------------
template<int MODE>
__global__ __launch_bounds__(512) void gemm256(
    const bf16* __restrict__ A, int lda, long sA,
    const bf16* __restrict__ B, int ldb, long sB,
    const float* __restrict__ bias,
    void* __restrict__ Out,
    int K, int ldo, long zstride)
{
  __shared__ bf16 lds[65536];   // 128 KiB
  const int tid = threadIdx.x, lane = tid & 63, wid = tid >> 6;
  const int wr = wid >> 2, wc = wid & 3;       // 2x4 wave grid
  const int m0 = blockIdx.y * 256, n0 = blockIdx.x * 256;
  const int z = blockIdx.z;
  const bf16* Ab = A + (long)z * sA;
  const bf16* Bb = B + (long)z * sB;
  const int nt = K >> 6;        // even, >= 4

  f32x4 acc[8][4] = {};

  auto STAGE = [&](int par, int t, int part) {
    const bf16* src = (part < 2) ? Ab : Bb;
    const int ld = (part < 2) ? lda : ldb;
    const int rb = ((part < 2) ? m0 : n0) + (part & 1) * 128;
    const int k0 = t << 6;
    bf16* dst = &lds[(par * 4 + part) * 8192];
#pragma unroll
    for (int j = 0; j < 2; ++j) {
      int idx = j * 512 + tid;            // 0..1023 chunk of 16B
      int row = idx >> 3;                 // 0..127
      int ce = ((idx & 7) ^ (row & 7)) << 3;  // pre-swizzled source column
      gload_lds16(src + (long)(rb + row) * ld + k0 + ce, dst + idx * 8);
    }
  };
  auto load_a = [&](bf16x8 (&a_)[4][2], int par, int mh) {
#pragma unroll
    for (int mf = 0; mf < 4; ++mf)
#pragma unroll
      for (int kk = 0; kk < 2; ++kk) {
        int r = mh * 64 + mf * 16 + (lane & 15);
        int cb = (kk * 64 + ((lane >> 4) << 4)) ^ ((r & 7) << 4);
        a_[mf][kk] = *(const bf16x8*)&lds[(par * 4 + wr) * 8192 + r * 64 + (cb >> 1)];
      }
  };
  auto load_b = [&](bf16x8 (&b_)[2][2], int par, int nh) {
#pragma unroll
    for (int nf = 0; nf < 2; ++nf)
#pragma unroll
      for (int kk = 0; kk < 2; ++kk) {
        int r = (wc & 1) * 64 + (nh * 2 + nf) * 16 + (lane & 15);
        int cb = (kk * 64 + ((lane >> 4) << 4)) ^ ((r & 7) << 4);
        b_[nf][kk] = *(const bf16x8*)&lds[(par * 4 + 2 + (wc >> 1)) * 8192 + r * 64 + (cb >> 1)];
      }
  };
  auto qmfma = [&](bf16x8 (&a_)[4][2], bf16x8 (&b_)[2][2], int mh, int nh) {
    __builtin_amdgcn_s_setprio(1);
#pragma unroll
    for (int mf = 0; mf < 4; ++mf)
#pragma unroll
      for (int nf = 0; nf < 2; ++nf)
#pragma unroll
        for (int kk = 0; kk < 2; ++kk)
          acc[mh * 4 + mf][nh * 2 + nf] =
              mfma16(a_[mf][kk], b_[nf][kk], acc[mh * 4 + mf][nh * 2 + nf]);
    __builtin_amdgcn_s_setprio(0);
  };

  // prologue: tile0 {A0,A1,B0,B1}, then 1.B0, 1.A0 (stay in flight)
  STAGE(0, 0, 0); STAGE(0, 0, 1); STAGE(0, 0, 2); STAGE(0, 0, 3);
  STAGE(1, 1, 2); STAGE(1, 1, 0);
  VMC(4);
  BAR();

  const int half = nt >> 1;
  for (int i = 0; i < half; ++i) {
    const int u = 2 * i;
    const bool full = (i < half - 1);
    bf16x8 a[4][2], b0[2][2], b1[2][2];
    // ======== tile u (parity 0) ========
    // ph1: quadrant (mh0,nh0); stage (u+1).B1
    load_a(a, 0, 0); load_b(b0, 0, 0);
    STAGE(1, u + 1, 3);
    BAR();
    qmfma(a, b0, 0, 0);
    BAR();
    // ph2: (mh0,nh1); stage (u+1).A1
    load_b(b1, 0, 1);
    STAGE(1, u + 1, 1);
    BAR();
    qmfma(a, b1, 0, 1);
    BAR();
    // ph3: (mh1,nh1); stage (u+2).B0
    load_a(a, 0, 1);
    if (full) STAGE(0, u + 2, 2);
    BAR();
    qmfma(a, b1, 1, 1);
    BAR();
    // ph4: (mh1,nh0); stage (u+2).A0; tile u+1 must land
    if (full) STAGE(0, u + 2, 0);
    BAR();
    qmfma(a, b0, 1, 0);
    if (full) { VMC(4); } else { VMC(0); }
    BAR();
    // ======== tile u+1 (parity 1) ========
    // ph5: (mh0,nh0); stage (u+2).B1
    load_a(a, 1, 0); load_b(b0, 1, 0);
    if (full) STAGE(0, u + 2, 3);
    BAR();
    qmfma(a, b0, 0, 0);
    BAR();
    // ph6: (mh0,nh1); stage (u+2).A1
    load_b(b1, 1, 1);
    if (full) STAGE(0, u + 2, 1);
    BAR();
    qmfma(a, b1, 0, 1);
    BAR();
    // ph7: (mh1,nh1); stage (u+3).B0
    load_a(a, 1, 1);
    if (full) STAGE(1, u + 3, 2);
    BAR();
    qmfma(a, b1, 1, 1);
    BAR();
    // ph8: (mh1,nh0); stage (u+3).A0; tile u+2 must land
    if (full) STAGE(1, u + 3, 0);
    BAR();
    qmfma(a, b0, 1, 0);
    if (full) VMC(4);
    BAR();
  }

  // epilogue: C/D layout col=lane&15, row=(lane>>4)*4+j  [HW-verified m89/m91]
  const int cb0 = n0 + wc * 64 + (lane & 15);
  const int rb0 = m0 + wr * 128 + ((lane >> 4) << 2);
#pragma unroll
  for (int mf = 0; mf < 8; ++mf) {
#pragma unroll
    for (int nf = 0; nf < 4; ++nf) {
      int c = cb0 + nf * 16;
#pragma unroll
      for (int j = 0; j < 4; ++j) {
        int rr = rb0 + mf * 16 + j;
        float v = acc[mf][nf][j];
        if constexpr (MODE == 0) {
          ((bf16*)Out)[(long)rr * ldo + c] = __float2bfloat16(v + bias[c]);
        } else if constexpr (MODE == 2) {
          float t2 = fmaxf(v + bias[c], 0.0f);
          ((bf16*)Out)[(long)rr * ldo + c] = __float2bfloat16(t2 * t2);
        } else { // MODE 5
          ((float*)Out)[(long)z * zstride + (long)rr * ldo + c] = v;
        }
      }
    }
  }
}

// ---------------------------------------------------------------------------
// Split-K reduce: out = sum_z part[z] + bias + resid   (all fp32, float4)
// ---------------------------------------------------------------------------
template<int SK>
__global__ __launch_bounds__(256) void reduce_k(
    const float* __restrict__ part, const float* __restrict__ bias,
    const float* __restrict__ resid, float* __restrict__ out,
    int ldo4, long total4)
{
  long i = (long)blockIdx.x * 256 + threadIdx.x;
  if (i >= total4) return;
  const float4* p4 = (const float4*)part;
  float4 s = p4[i];
#pragma unroll
  for (int z = 1; z < SK; ++z) {
    float4 t = p4[(long)z * total4 + i];
    s.x += t.x; s.y += t.y; s.z += t.z; s.w += t.w;
  }
  float4 b = ((const float4*)bias)[(int)(i % ldo4)];
  float4 r = ((const float4*)resid)[i];
  s.x += b.x + r.x; s.y += b.y + r.y; s.z += b.z + r.z; s.w += b.w + r.w;
  ((float4*)out)[i] = s;
}

// ---------------------------------------------------------------------------
// Fused flash attention. One block per (q-tile of 128, (b,h)).
// qh pre-scaled by 0.125*log2e so softmax runs in exp2 domain.
// 256 threads = 4 waves; wave w owns q-rows [w*32, w*32+32).
// K tiles of 64 kv, double-buffered; V^T consumed from vt (B,H,64,576).
// ---------------------------------------------------------------------------
__global__ __launch_bounds__(256) void flash_attn(
    const bf16* __restrict__ qh, const bf16* __restrict__ kh,
    const bf16* __restrict__ vt, bf16* __restrict__ attn)
{
  __shared__ bf16 ks[2][64 * 64];    // K tile  [kv][d]
  __shared__ bf16 vs[2][64 * 64];    // V^T tile [d][kv]
  __shared__ bf16 pq[128 * 64];      // Q stage, then P (wave-private rows)
  const int tid = threadIdx.x, lane = tid & 63, wv = tid >> 6;
  const int qt = blockIdx.x, zh = blockIdx.y;
  const int b = zh >> 4, h = zh & 15;
  const int q0 = qt * 128;
  const bf16* qb = qh + (long)zh * 32768 + (long)q0 * 64;
  const bf16* kb = kh + (long)zh * 36864;
  const bf16* vb = vt + (long)zh * 36864;

  // stage Q tile (128x64)
#pragma unroll
  for (int i = 0; i < 4; ++i) {
    int idx = i * 256 + tid;
    gload_lds16(qb + (long)(idx >> 3) * 64 + ((idx & 7) << 3), pq + idx * 8);
  }
  auto stage_kv = [&](int bb, int j) {
#pragma unroll
    for (int it = 0; it < 2; ++it) {
      int idx = it * 256 + tid;   // K rows
      gload_lds16(kb + (long)(j * 64 + (idx >> 3)) * 64 + ((idx & 7) << 3), &ks[bb][idx * 8]);
    }
#pragma unroll
    for (int it = 0; it < 2; ++it) {
      int idx = it * 256 + tid;   // V^T rows (d)
      gload_lds16(vb + (long)(idx >> 3) * 576 + j * 64 + ((idx & 7) << 3), &vs[bb][idx * 8]);
    }
  };
  stage_kv(0, 0);
  VMC(0);
  BAR();

  // hoist Q fragments to registers (wave-private rows)
  bf16x8 qf[2][2];
#pragma unroll
  for (int m = 0; m < 2; ++m)
#pragma unroll
    for (int kk = 0; kk < 2; ++kk)
      qf[m][kk] = *(const bf16x8*)&pq[(wv * 32 + m * 16 + (lane & 15)) * 64 + kk * 32 + ((lane >> 4) << 3)];

  f32x4 acc_o[2][4] = {};
  float mrun[2][4], lrun[2][4];
#pragma unroll
  for (int m = 0; m < 2; ++m)
#pragma unroll
    for (int jj = 0; jj < 4; ++jj) { mrun[m][jj] = -1e30f; lrun[m][jj] = 0.0f; }

  const int nkv = qt * 2 + 3;   // max col needed = q0+191 -> q0/64+3 tiles
  int cur = 0;
  for (int j = 0; j < nkv; ++j) {
    if (j + 1 < nkv) stage_kv(cur ^ 1, j + 1);

    // S = Q K^T (already in log2 domain via Q pre-scale)
    f32x4 s[2][4] = {};
#pragma unroll
    for (int kk = 0; kk < 2; ++kk) {
      bf16x8 kf[4];
#pragma unroll
      for (int n = 0; n < 4; ++n)
        kf[n] = *(const bf16x8*)&ks[cur][(n * 16 + (lane & 15)) * 64 + kk * 32 + ((lane >> 4) << 3)];
#pragma unroll
      for (int m = 0; m < 2; ++m)
#pragma unroll
        for (int n = 0; n < 4; ++n)
          s[m][n] = mfma16(qf[m][kk], kf[n], s[m][n]);
    }
    // causal mask: allowed col <= q_global + 64
#pragma unroll
    for (int m = 0; m < 2; ++m)
#pragma unroll
      for (int n = 0; n < 4; ++n) {
        int c = j * 64 + n * 16 + (lane & 15);
#pragma unroll
        for (int jj = 0; jj < 4; ++jj) {
          int r = q0 + wv * 32 + m * 16 + ((lane >> 4) << 2) + jj;
          if (c > r + 64) s[m][n][jj] = -1e30f;
        }
      }
    // online softmax per row (row owned by 16-lane group)
#pragma unroll
    for (int m = 0; m < 2; ++m)
#pragma unroll
      for (int jj = 0; jj < 4; ++jj) {
        float pm = fmaxf(fmaxf(s[m][0][jj], s[m][1][jj]), fmaxf(s[m][2][jj], s[m][3][jj]));
#pragma unroll
        for (int off = 1; off < 16; off <<= 1) pm = fmaxf(pm, __shfl_xor(pm, off));
        float mnew = fmaxf(mrun[m][jj], pm);
        float sc = exp2f(mrun[m][jj] - mnew);
        mrun[m][jj] = mnew;
        float rs = 0.0f;
#pragma unroll
        for (int n = 0; n < 4; ++n) {
          float p = exp2f(s[m][n][jj] - mnew);
          s[m][n][jj] = p;
          rs += p;
        }
#pragma unroll
        for (int off = 1; off < 16; off <<= 1) rs += __shfl_xor(rs, off);
        lrun[m][jj] = lrun[m][jj] * sc + rs;
#pragma unroll
        for (int nd = 0; nd < 4; ++nd) acc_o[m][nd][jj] *= sc;
      }
    // P -> bf16 in wave-private LDS rows (C-layout -> A-layout transpose)
#pragma unroll
    for (int m = 0; m < 2; ++m)
#pragma unroll
      for (int n = 0; n < 4; ++n)
#pragma unroll
        for (int jj = 0; jj < 4; ++jj)
          pq[(wv * 32 + m * 16 + ((lane >> 4) << 2) + jj) * 64 + n * 16 + (lane & 15)] =
              __float2bfloat16(s[m][n][jj]);
    // O += P * V^T
#pragma unroll
    for (int kk = 0; kk < 2; ++kk) {
      bf16x8 pa[2], vf[4];
#pragma unroll
      for (int m = 0; m < 2; ++m)
        pa[m] = *(const bf16x8*)&pq[(wv * 32 + m * 16 + (lane & 15)) * 64 + kk * 32 + ((lane >> 4) << 3)];
#pragma unroll
      for (int nd = 0; nd < 4; ++nd)
        vf[nd] = *(const bf16x8*)&vs[cur][(nd * 16 + (lane & 15)) * 64 + kk * 32 + ((lane >> 4) << 3)];
#pragma unroll
      for (int m = 0; m < 2; ++m)
#pragma unroll
        for (int nd = 0; nd < 4; ++nd)
          acc_o[m][nd] = mfma16(pa[m], vf[nd], acc_o[m][nd]);
    }
    if (j + 1 < nkv) {
      asm volatile("s_waitcnt lgkmcnt(0)" ::: "memory");
      VMC(0);
      BAR();
      cur ^= 1;
    }
  }
  // epilogue: O / l, scatter into attn (B*T, D) at head column h*64
  bf16* ob = attn + ((long)b * 512 + q0) * 1024 + h * 64;
#pragma unroll
  for (int m = 0; m < 2; ++m)
#pragma unroll
    for (int jj = 0; jj < 4; ++jj) {
      float inv = 1.0f / lrun[m][jj];
      int r = wv * 32 + m * 16 + ((lane >> 4) << 2) + jj;
#pragma unroll
      for (int nd = 0; nd < 4; ++nd)
        ob[(long)r * 1024 + nd * 16 + (lane & 15)] = __float2bfloat16(acc_o[m][nd][jj] * inv);
    }
}

// ---------------------------------------------------------------------------
// LayerNorm over D=1024, one block per row. CONCAT: row from [memory|x].
// ---------------------------------------------------------------------------
template<bool CONCAT>
__global__ __launch_bounds__(256) void ln_kernel(
    const float* __restrict__ xin, const float* __restrict__ mem,
    const float* __restrict__ g, const float* __restrict__ beta,
    bf16* __restrict__ out)
{
  const int row = blockIdx.x;
  const float* src;
  if (CONCAT) {
    int b = row / 576, p = row % 576;
    src = (p < 64) ? (mem + ((long)b * 64 + p) * 1024)
                   : (xin + ((long)b * 512 + (p - 64)) * 1024);
  } else {
    src = xin + (long)row * 1024;
  }
  const int tid = threadIdx.x;
  float4 v = ((const float4*)src)[tid];
  float s = v.x + v.y + v.z + v.w;
  float s2 = v.x * v.x + v.y * v.y + v.z * v.z + v.w * v.w;
#pragma unroll
  for (int o = 32; o; o >>= 1) {
    s += __shfl_down(s, o);
    s2 += __shfl_down(s2, o);
  }
  __shared__ float red[8];
  const int w = tid >> 6, lane = tid & 63;
  if (lane == 0) { red[w] = s; red[4 + w] = s2; }
  __syncthreads();
  float S = red[0] + red[1] + red[2] + red[3];
  float S2 = red[4] + red[5] + red[6] + red[7];
  float mu = S * (1.0f / 1024.0f);
  float rs = rsqrtf(S2 * (1.0f / 1024.0f) - mu * mu + 1e-5f);
  float4 gg = ((const float4*)g)[tid];
  float4 bb = ((const float4*)beta)[tid];
  bf16x4s o4;
  o4.a = __float2bfloat16((v.x - mu) * rs * gg.x + bb.x);
  o4.b = __float2bfloat16((v.y - mu) * rs * gg.y + bb.y);
  o4.c = __float2bfloat16((v.z - mu) * rs * gg.z + bb.z);
  o4.d = __float2bfloat16((v.w - mu) * rs * gg.w + bb.w);
  *(bf16x4s*)(out + (long)row * 1024 + tid * 4) = o4;
}

// ---------------------------------------------------------------------------
// fp32 weights -> bf16, all 6 matrices packed [Wq|Wk|Wv|Wo|W1|W2]
// ---------------------------------------------------------------------------
__global__ __launch_bounds__(256) void cvt_weights(
    const float* __restrict__ wq, const float* __restrict__ wk,
    const float* __restrict__ wv, const float* __restrict__ wo,
    const float* __restrict__ w1, const float* __restrict__ w2,
    bf16* __restrict__ out)
{
  long e = ((long)blockIdx.x * 256 + threadIdx.x) * 4;
  const long DD = 1048576, DF = 4194304;
  const float* src; long base;
  if (e < DD)            { src = wq; base = 0; }
  else if (e < 2 * DD)   { src = wk; base = DD; }
  else if (e < 3 * DD)   { src = wv; base = 2 * DD; }
  else if (e < 4 * DD)   { src = wo; base = 3 * DD; }
  else if (e < 4 * DD + DF) { src = w1; base = 4 * DD; }
  else                   { src = w2; base = 4 * DD + DF; }
  float4 v = *(const float4*)(src + (e - base));
  bf16x4s o4;
  o4.a = __float2bfloat16(v.x);
  o4.b = __float2bfloat16(v.y);
  o4.c = __float2bfloat16(v.z);
  o4.d = __float2bfloat16(v.w);
  *(bf16x4s*)(out + e) = o4;
}

__global__ __launch_bounds__(256) void bias_concat(
    const float* __restrict__ bq, const float* __restrict__ bk,
    const float* __restrict__ bv, float* __restrict__ out)
{
  int i = blockIdx.x * 256 + threadIdx.x;
  if (i < 1024)      out[i] = bq[i];
  else if (i < 2048) out[i] = bk[i - 1024];
  else if (i < 3072) out[i] = bv[i - 2048];
}

// cos/sin table for RoPE: tab[p*16+f] = cos(p * 10000^(-f/16)), +9216 for sin
__global__ __launch_bounds__(256) void rope_tab_kernel(float* __restrict__ tab)
{
  int i = blockIdx.x * 256 + threadIdx.x;
  if (i >= 9216) return;
  int p = i >> 4, f = i & 15;
  float invf = expf(-(float)f * 0.5756462732485114f);  // 10000^(-f/16)
  float ang = (float)p * invf;
  tab[i] = cosf(ang);
  tab[9216 + i] = sinf(ang);
}

// ---------------------------------------------------------------------------
// RoPE + head-layout reshape. Q is pre-scaled by 0.125*log2(e) so the fused
// attention computes softmax in the exp2 domain.
// qkv: (B*L, 3072) bf16 -> qh (B,H,T,64) [rows p>=64], kh (B,H,L,64),
// vt (B,H,64,L) [transposed for PV B^T MFMA].
// ---------------------------------------------------------------------------
__global__ __launch_bounds__(256) void rope_reshape(
    const bf16* __restrict__ qkv, const float* __restrict__ tab,
    bf16* __restrict__ qh, bf16* __restrict__ kh, bf16* __restrict__ vt)
{
  const float QSCALE = 0.18033688011112043f;  // 0.125 * log2(e)
  long i = (long)blockIdx.x * 256 + threadIdx.x;
  if (i >= 8L * 576 * 1024) return;
  int dfull = (int)(i & 1023);
  long bp = i >> 10;
  int p = (int)(bp % 576);
  int b = (int)(bp / 576);
  int h = dfull >> 6, d = dfull & 63;
  const bf16* rowp = qkv + bp * 3072;

  float cosv = 1.0f, sinv = 0.0f;
  const bool rot = d < 32;
  int pd = 0;
  if (rot) {
    int i0 = d & 15;
    cosv = tab[p * 16 + i0];
    sinv = tab[9216 + p * 16 + i0];
    pd = (d < 16) ? d + 16 : d - 16;
  }
  // K (+RoPE)
  {
    float v0 = __bfloat162float(rowp[1024 + dfull]);
    float ov = v0;
    if (rot) {
      float v1 = __bfloat162float(rowp[1024 + (h << 6) + pd]);
      ov = (d < 16) ? (v0 * cosv - v1 * sinv) : (v0 * cosv + v1 * sinv);
    }
    kh[(((long)b * 16 + h) * 576 + p) * 64 + d] = __float2bfloat16(ov);
  }
  // V transpose
  vt[(((long)b * 16 + h) * 64 + d) * 576 + p] = rowp[2048 + dfull];
  // Q (+RoPE, + scale), only the T query rows
  if (p >= 64) {
    float v0 = __bfloat162float(rowp[dfull]);
    float ov = v0;
    if (rot) {
      float v1 = __bfloat162float(rowp[(h << 6) + pd]);
      ov = (d < 16) ? (v0 * cosv - v1 * sinv) : (v0 * cosv + v1 * sinv);
    }
    qh[(((long)b * 16 + h) * 512 + (p - 64)) * 64 + d] = __float2bfloat16(ov * QSCALE);
  }
}

// ---------------------------------------------------------------------------
extern "C" void kernel_launch(void* const* d_in, const int* in_sizes, int n_in,
                              void* d_out, int out_size, void* d_ws, size_t ws_size,
                              hipStream_t stream)
{
  (void)in_sizes; (void)n_in; (void)out_size; (void)ws_size;
  const float* x    = (const float*)d_in[0];
  const float* mem  = (const float*)d_in[1];
  const float* Wq   = (const float*)d_in[2];
  const float* bq   = (const float*)d_in[3];
  const float* Wk   = (const float*)d_in[4];
  const float* bk   = (const float*)d_in[5];
  const float* Wv   = (const float*)d_in[6];
  const float* bv   = (const float*)d_in[7];
  const float* Wo   = (const float*)d_in[8];
  const float* bo   = (const float*)d_in[9];
  const float* W1   = (const float*)d_in[10];
  const float* b1   = (const float*)d_in[11];
  const float* W2   = (const float*)d_in[12];
  const float* b2   = (const float*)d_in[13];
  const float* g_a  = (const float*)d_in[14];
  const float* bt_a = (const float*)d_in[15];
  const float* g_m  = (const float*)d_in[16];
  const float* bt_m = (const float*)d_in[17];
  float* out = (float*)d_out;

  char* ws = (char*)d_ws;
  size_t off = 0;
  auto carve = [&](size_t bytes) -> void* {
    void* p = ws + off;
    off = (off + bytes + 255) & ~(size_t)255;
    return p;
  };
  bf16*  wB    = (bf16*)carve(12582912L * 2);        // packed bf16 weights
  float* bqkv  = (float*)carve(3072 * 4);
  float* rtab  = (float*)carve(9216 * 2 * 4);        // rope cos/sin table
  bf16*  xa    = (bf16*)carve(4608L * 1024 * 2);     // LN1 out
  bf16*  qkv   = (bf16*)carve(4608L * 3072 * 2);     // QKV GEMM out
  bf16*  qh    = (bf16*)carve(8L * 16 * 512 * 64 * 2);
  bf16*  kh    = (bf16*)carve(8L * 16 * 576 * 64 * 2);
  bf16*  vt    = (bf16*)carve(8L * 16 * 576 * 64 * 2);
  bf16*  attn  = (bf16*)carve(4096L * 1024 * 2);     // flash out, (B*T, D)
  float* x2    = (float*)carve(4096L * 1024 * 4);    // post-attn residual
  bf16*  xn    = (bf16*)carve(4096L * 1024 * 2);     // LN2 out
  bf16*  hbuf  = (bf16*)carve(4096L * 4096 * 2);     // relu^2 hidden
  float* parts = (float*)carve(4L * 4096 * 1024 * 4);// split-K partials (67MB)

  cvt_weights<<<12288, 256, 0, stream>>>(Wq, Wk, Wv, Wo, W1, W2, wB);
  bias_concat<<<12, 256, 0, stream>>>(bq, bk, bv, bqkv);
  rope_tab_kernel<<<36, 256, 0, stream>>>(rtab);
  ln_kernel<true><<<4608, 256, 0, stream>>>(x, mem, g_a, bt_a, xa);

  // QKV: (4608,1024) x (3072,1024)^T -> (4608,3072)   grid (12,18) = 216
  gemm256<0><<<dim3(12, 18, 1), 512, 0, stream>>>(
      xa, 1024, 0, wB, 1024, 0, bqkv, qkv, 1024, 3072, 0);

  rope_reshape<<<18432, 256, 0, stream>>>(qkv, rtab, qh, kh, vt);

  // fused flash attention: grid (q-tile, b*h)
  flash_attn<<<dim3(4, 128), 256, 0, stream>>>(qh, kh, vt, attn);

  // Wo split-K=4: (4096,1024)x(1024,1024)^T, slice K=256 -> grid (4,16,4)=256
  gemm256<5><<<dim3(4, 16, 4), 512, 0, stream>>>(
      attn, 1024, 256, wB + 3145728L, 1024, 256, nullptr, parts, 256, 1024, 4194304L);
  reduce_k<4><<<4096, 256, 0, stream>>>(parts, bo, x, x2, 256, 1048576);

  ln_kernel<false><<<4096, 256, 0, stream>>>(x2, nullptr, g_m, bt_m, xn);

  // W1 + relu^2: (4096,1024)x(4096,1024)^T -> (4096,4096) bf16, grid (16,16)
  gemm256<2><<<dim3(16, 16, 1), 512, 0, stream>>>(
      xn, 1024, 0, wB + 4194304L, 1024, 0, b1, hbuf, 1024, 4096, 0);

  // W2 split-K=4: (4096,4096)x(1024,4096)^T, slice K=1024 -> grid (4,16,4)=256
  gemm256<5><<<dim3(4, 16, 4), 512, 0, stream>>>(
      hbuf, 4096, 1024, wB + 8388608L, 4096, 1024, nullptr, parts, 1024, 1024, 4194304L);
  reduce_k<4><<<4096, 256, 0, stream>>>(parts, b2, x2, out, 256, 1048576);
}

// Round 5
// 258.012 us; speedup vs baseline: 1.9357x; 1.0632x over previous
//
#include <hip/hip_runtime.h>
#include <hip/hip_bf16.h>
#include <cmath>

// Problem constants: B=8 T=512 M=64 D=1024 H=16 DFF=4096, DH=64, ROT=32, L=576
using bf16 = __hip_bfloat16;
typedef __attribute__((ext_vector_type(8))) __bf16 bf16x8;
typedef __attribute__((ext_vector_type(4))) float f32x4;

struct __align__(8) bf16x4s { bf16 a, b, c, d; };

__device__ inline void gload_lds16(const void* g, void* l) {
  __builtin_amdgcn_global_load_lds(
      (__attribute__((address_space(1))) void*)g,
      (__attribute__((address_space(3))) void*)l, 16, 0, 0);
}

__device__ inline f32x4 mfma16(bf16x8 a, bf16x8 b, f32x4 c) {
  return __builtin_amdgcn_mfma_f32_16x16x32_bf16(a, b, c, 0, 0, 0);
}

#define BAR() __builtin_amdgcn_s_barrier()
#define VMC(N) asm volatile("s_waitcnt vmcnt(" #N ")" ::: "memory")
#define LGKM0() asm volatile("s_waitcnt lgkmcnt(0)" ::: "memory")

// ---------------------------------------------------------------------------
// C = A * B^T, 256x256 tile, BK=64, 512 threads (8 waves, 2x4; per-wave
// 128x64 output). 8-phase schedule, counted vmcnt(4) at phases 4/8 only.
// LDS: 8 half-slots x 16KB (2-tile ring): [par*4 + {A0,A1,B0,B1}].
// XOR swizzle byte^=((row&7)<<4): linear gload_lds dest + pre-swizzled global
// source; ds_reads apply the same XOR -> conflict-free b128 fragment reads.
// blockIdx.z = split-K slice (A,B k-offset z*sA / z*sB elements).
// MODE 0: bf16 out = acc + bias[c]
// MODE 2: bf16 out = relu(acc + bias[c])^2
// MODE 5: fp32 partial: Out[z*zstride + r*ldo + c] = acc
// ---------------------------------------------------------------------------
template<int MODE>
__global__ __launch_bounds__(512) void gemm256(
    const bf16* __restrict__ A, int lda, long sA,
    const bf16* __restrict__ B, int ldb, long sB,
    const float* __restrict__ bias,
    void* __restrict__ Out,
    int K, int ldo, long zstride)
{
  __shared__ bf16 lds[65536];   // 128 KiB
  const int tid = threadIdx.x, lane = tid & 63, wid = tid >> 6;
  const int wr = wid >> 2, wc = wid & 3;       // 2x4 wave grid
  const int m0 = blockIdx.y * 256, n0 = blockIdx.x * 256;
  const int z = blockIdx.z;
  const bf16* Ab = A + (long)z * sA;
  const bf16* Bb = B + (long)z * sB;
  const int nt = K >> 6;        // even, >= 4

  f32x4 acc[8][4] = {};

  auto STAGE = [&](int par, int t, int part) {
    const bf16* src = (part < 2) ? Ab : Bb;
    const int ld = (part < 2) ? lda : ldb;
    const int rb = ((part < 2) ? m0 : n0) + (part & 1) * 128;
    const int k0 = t << 6;
    bf16* dst = &lds[(par * 4 + part) * 8192];
#pragma unroll
    for (int j = 0; j < 2; ++j) {
      int idx = j * 512 + tid;            // 0..1023 chunk of 16B
      int row = idx >> 3;                 // 0..127
      int ce = ((idx & 7) ^ (row & 7)) << 3;  // pre-swizzled source column
      gload_lds16(src + (long)(rb + row) * ld + k0 + ce, dst + idx * 8);
    }
  };
  auto load_a = [&](bf16x8 (&a_)[4][2], int par, int mh) {
#pragma unroll
    for (int mf = 0; mf < 4; ++mf)
#pragma unroll
      for (int kk = 0; kk < 2; ++kk) {
        int r = mh * 64 + mf * 16 + (lane & 15);
        int cb = (kk * 64 + ((lane >> 4) << 4)) ^ ((r & 7) << 4);
        a_[mf][kk] = *(const bf16x8*)&lds[(par * 4 + wr) * 8192 + r * 64 + (cb >> 1)];
      }
  };
  auto load_b = [&](bf16x8 (&b_)[2][2], int par, int nh) {
#pragma unroll
    for (int nf = 0; nf < 2; ++nf)
#pragma unroll
      for (int kk = 0; kk < 2; ++kk) {
        int r = (wc & 1) * 64 + (nh * 2 + nf) * 16 + (lane & 15);
        int cb = (kk * 64 + ((lane >> 4) << 4)) ^ ((r & 7) << 4);
        b_[nf][kk] = *(const bf16x8*)&lds[(par * 4 + 2 + (wc >> 1)) * 8192 + r * 64 + (cb >> 1)];
      }
  };
  auto qmfma = [&](bf16x8 (&a_)[4][2], bf16x8 (&b_)[2][2], int mh, int nh) {
    __builtin_amdgcn_s_setprio(1);
#pragma unroll
    for (int mf = 0; mf < 4; ++mf)
#pragma unroll
      for (int nf = 0; nf < 2; ++nf)
#pragma unroll
        for (int kk = 0; kk < 2; ++kk)
          acc[mh * 4 + mf][nh * 2 + nf] =
              mfma16(a_[mf][kk], b_[nf][kk], acc[mh * 4 + mf][nh * 2 + nf]);
    __builtin_amdgcn_s_setprio(0);
  };

  // prologue: tile0 {A0,A1,B0,B1}, then 1.B0, 1.A0 (stay in flight)
  STAGE(0, 0, 0); STAGE(0, 0, 1); STAGE(0, 0, 2); STAGE(0, 0, 3);
  STAGE(1, 1, 2); STAGE(1, 1, 0);
  VMC(4);
  BAR();

  const int half = nt >> 1;
  for (int i = 0; i < half; ++i) {
    const int u = 2 * i;
    const bool full = (i < half - 1);
    bf16x8 a[4][2], b0[2][2], b1[2][2];
    // ======== tile u (parity 0) ========
    load_a(a, 0, 0); load_b(b0, 0, 0);
    STAGE(1, u + 1, 3);
    BAR();
    qmfma(a, b0, 0, 0);
    BAR();
    load_b(b1, 0, 1);
    STAGE(1, u + 1, 1);
    BAR();
    qmfma(a, b1, 0, 1);
    BAR();
    load_a(a, 0, 1);
    if (full) STAGE(0, u + 2, 2);
    BAR();
    qmfma(a, b1, 1, 1);
    BAR();
    if (full) STAGE(0, u + 2, 0);
    BAR();
    qmfma(a, b0, 1, 0);
    if (full) { VMC(4); } else { VMC(0); }
    BAR();
    // ======== tile u+1 (parity 1) ========
    load_a(a, 1, 0); load_b(b0, 1, 0);
    if (full) STAGE(0, u + 2, 3);
    BAR();
    qmfma(a, b0, 0, 0);
    BAR();
    load_b(b1, 1, 1);
    if (full) STAGE(0, u + 2, 1);
    BAR();
    qmfma(a, b1, 0, 1);
    BAR();
    load_a(a, 1, 1);
    if (full) STAGE(1, u + 3, 2);
    BAR();
    qmfma(a, b1, 1, 1);
    BAR();
    if (full) STAGE(1, u + 3, 0);
    BAR();
    qmfma(a, b0, 1, 0);
    if (full) VMC(4);
    BAR();
  }

  // epilogue: C/D layout col=lane&15, row=(lane>>4)*4+j  [HW-verified m89/m91]
  const int cb0 = n0 + wc * 64 + (lane & 15);
  const int rb0 = m0 + wr * 128 + ((lane >> 4) << 2);
#pragma unroll
  for (int mf = 0; mf < 8; ++mf) {
#pragma unroll
    for (int nf = 0; nf < 4; ++nf) {
      int c = cb0 + nf * 16;
#pragma unroll
      for (int j = 0; j < 4; ++j) {
        int rr = rb0 + mf * 16 + j;
        float v = acc[mf][nf][j];
        if constexpr (MODE == 0) {
          ((bf16*)Out)[(long)rr * ldo + c] = __float2bfloat16(v + bias[c]);
        } else if constexpr (MODE == 2) {
          float t2 = fmaxf(v + bias[c], 0.0f);
          ((bf16*)Out)[(long)rr * ldo + c] = __float2bfloat16(t2 * t2);
        } else { // MODE 5
          ((float*)Out)[(long)z * zstride + (long)rr * ldo + c] = v;
        }
      }
    }
  }
}

// ---------------------------------------------------------------------------
// Split-K reduce: out = sum_z part[z] + bias + resid   (all fp32, float4)
// ---------------------------------------------------------------------------
template<int SK>
__global__ __launch_bounds__(256) void reduce_k(
    const float* __restrict__ part, const float* __restrict__ bias,
    const float* __restrict__ resid, float* __restrict__ out,
    int ldo4, long total4)
{
  long i = (long)blockIdx.x * 256 + threadIdx.x;
  if (i >= total4) return;
  const float4* p4 = (const float4*)part;
  float4 s = p4[i];
#pragma unroll
  for (int z = 1; z < SK; ++z) {
    float4 t = p4[(long)z * total4 + i];
    s.x += t.x; s.y += t.y; s.z += t.z; s.w += t.w;
  }
  float4 b = ((const float4*)bias)[(int)(i % ldo4)];
  float4 r = ((const float4*)resid)[i];
  s.x += b.x + r.x; s.y += b.y + r.y; s.z += b.z + r.z; s.w += b.w + r.w;
  ((float4*)out)[i] = s;
}

// ---------------------------------------------------------------------------
// Fused split-K(4) reduce + residual + LayerNorm. One block per row (D=1024).
// x2 = sum_z part[z] + bias + resid;  xn = LN(x2)*g + beta  (bf16)
// ---------------------------------------------------------------------------
__global__ __launch_bounds__(256) void reduce_ln(
    const float* __restrict__ part, const float* __restrict__ bias,
    const float* __restrict__ resid, const float* __restrict__ g,
    const float* __restrict__ beta, float* __restrict__ x2,
    bf16* __restrict__ xn)
{
  const int row = blockIdx.x, tid = threadIdx.x;
  const long rb = (long)row * 1024;
  float4 v = ((const float4*)(part + rb))[tid];
#pragma unroll
  for (int z = 1; z < 4; ++z) {
    float4 t = ((const float4*)(part + (long)z * 4194304 + rb))[tid];
    v.x += t.x; v.y += t.y; v.z += t.z; v.w += t.w;
  }
  float4 bb4 = ((const float4*)bias)[tid];
  float4 rr4 = ((const float4*)(resid + rb))[tid];
  v.x += bb4.x + rr4.x; v.y += bb4.y + rr4.y;
  v.z += bb4.z + rr4.z; v.w += bb4.w + rr4.w;
  ((float4*)(x2 + rb))[tid] = v;

  float s = v.x + v.y + v.z + v.w;
  float s2 = v.x * v.x + v.y * v.y + v.z * v.z + v.w * v.w;
#pragma unroll
  for (int o = 32; o; o >>= 1) {
    s += __shfl_down(s, o);
    s2 += __shfl_down(s2, o);
  }
  __shared__ float red[8];
  const int w = tid >> 6, lane = tid & 63;
  if (lane == 0) { red[w] = s; red[4 + w] = s2; }
  __syncthreads();
  float S = red[0] + red[1] + red[2] + red[3];
  float S2 = red[4] + red[5] + red[6] + red[7];
  float mu = S * (1.0f / 1024.0f);
  float rs = rsqrtf(S2 * (1.0f / 1024.0f) - mu * mu + 1e-5f);
  float4 gg = ((const float4*)g)[tid];
  float4 be = ((const float4*)beta)[tid];
  bf16x4s o4;
  o4.a = __float2bfloat16((v.x - mu) * rs * gg.x + be.x);
  o4.b = __float2bfloat16((v.y - mu) * rs * gg.y + be.y);
  o4.c = __float2bfloat16((v.z - mu) * rs * gg.z + be.z);
  o4.d = __float2bfloat16((v.w - mu) * rs * gg.w + be.w);
  *(bf16x4s*)(xn + rb + tid * 4) = o4;
}

// ---------------------------------------------------------------------------
// Fused flash attention. Q-tile 64, 4 waves (wave owns 16 q-rows), KV tiles
// of 64, double-buffered. All LDS tiles XOR-swizzled (c ^= (row&7)<<3) via
// pre-swizzled global source for gload_lds + swizzled ds addresses.
// Block work permuted so the 8 q-tiles of one (b,h) share an XCD (L2 reuse).
// qh pre-scaled by 0.125*log2e; softmax in exp2 domain.
// ---------------------------------------------------------------------------
__global__ __launch_bounds__(256) void flash_attn(
    const bf16* __restrict__ qh, const bf16* __restrict__ kh,
    const bf16* __restrict__ vt, bf16* __restrict__ attn)
{
  __shared__ bf16 ks[2][64 * 64];    // K tile  [kv][d]
  __shared__ bf16 vs[2][64 * 64];    // V^T tile [d][kv]
  __shared__ bf16 pq[64 * 64];       // Q stage, then P (wave-private rows)
  const int tid = threadIdx.x, lane = tid & 63, wv = tid >> 6;
  const int bid = blockIdx.x;
  const int xcd = bid & 7, sl = bid >> 3;
  const int zh = xcd * 16 + (sl >> 3);   // (b,h) group pinned to one XCD
  const int qt = sl & 7;
  const int b = zh >> 4, h = zh & 15;
  const int q0 = qt * 64;
  const bf16* qb = qh + (long)zh * 32768 + (long)q0 * 64;
  const bf16* kb = kh + (long)zh * 36864;
  const bf16* vb = vt + (long)zh * 36864;

  // stage Q tile (64x64), pre-swizzled source
#pragma unroll
  for (int i = 0; i < 2; ++i) {
    int idx = i * 256 + tid;
    int row = idx >> 3;
    int ce = ((idx & 7) ^ (row & 7)) << 3;
    gload_lds16(qb + (long)row * 64 + ce, pq + idx * 8);
  }
  auto stage_kv = [&](int bb, int j) {
#pragma unroll
    for (int it = 0; it < 2; ++it) {
      int idx = it * 256 + tid;
      int row = idx >> 3;
      int ce = ((idx & 7) ^ (row & 7)) << 3;
      gload_lds16(kb + (long)(j * 64 + row) * 64 + ce, &ks[bb][idx * 8]);
    }
#pragma unroll
    for (int it = 0; it < 2; ++it) {
      int idx = it * 256 + tid;
      int row = idx >> 3;
      int ce = ((idx & 7) ^ (row & 7)) << 3;
      gload_lds16(vb + (long)row * 576 + j * 64 + ce, &vs[bb][idx * 8]);
    }
  };
  stage_kv(0, 0);
  VMC(0);
  BAR();

  // Q fragments (swizzled read), wave-private rows
  bf16x8 qf[2];
  {
    int r = wv * 16 + (lane & 15);
#pragma unroll
    for (int kk = 0; kk < 2; ++kk) {
      int c0 = kk * 32 + ((lane >> 4) << 3);
      qf[kk] = *(const bf16x8*)&pq[r * 64 + (c0 ^ ((r & 7) << 3))];
    }
  }

  f32x4 acc_o[4] = {};
  float mrun[4], lrun[4];
#pragma unroll
  for (int jj = 0; jj < 4; ++jj) { mrun[jj] = -1e30f; lrun[jj] = 0.0f; }

  const int nkv = qt + 2;   // tiles j<=qt fully unmasked; j=qt+1 diagonal
  int cur = 0;
  for (int j = 0; j < nkv; ++j) {
    if (j + 1 < nkv) stage_kv(cur ^ 1, j + 1);

    // S = Q K^T
    f32x4 sv[4] = {};
    __builtin_amdgcn_s_setprio(1);
#pragma unroll
    for (int kk = 0; kk < 2; ++kk) {
      bf16x8 kf[4];
      int c0 = kk * 32 + ((lane >> 4) << 3);
#pragma unroll
      for (int n = 0; n < 4; ++n) {
        int r = n * 16 + (lane & 15);
        kf[n] = *(const bf16x8*)&ks[cur][r * 64 + (c0 ^ ((r & 7) << 3))];
      }
#pragma unroll
      for (int n = 0; n < 4; ++n) sv[n] = mfma16(qf[kk], kf[n], sv[n]);
    }
    __builtin_amdgcn_s_setprio(0);

    // causal mask only on the diagonal tile (uniform branch)
    if (j == nkv - 1) {
#pragma unroll
      for (int n = 0; n < 4; ++n) {
        int c = n * 16 + (lane & 15);            // local col in tile
#pragma unroll
        for (int jj = 0; jj < 4; ++jj) {
          int r = wv * 16 + ((lane >> 4) << 2) + jj;  // local row
          if (c > r) sv[n][jj] = -1e30f;         // j*64 + c > q0 + r + 64
        }
      }
    }
    // online softmax (rows owned by 16-lane groups)
#pragma unroll
    for (int jj = 0; jj < 4; ++jj) {
      float pm = fmaxf(fmaxf(sv[0][jj], sv[1][jj]), fmaxf(sv[2][jj], sv[3][jj]));
#pragma unroll
      for (int off = 1; off < 16; off <<= 1) pm = fmaxf(pm, __shfl_xor(pm, off));
      float mnew = fmaxf(mrun[jj], pm);
      float sc = exp2f(mrun[jj] - mnew);
      mrun[jj] = mnew;
      float rs = 0.0f;
#pragma unroll
      for (int n = 0; n < 4; ++n) {
        float p = exp2f(sv[n][jj] - mnew);
        sv[n][jj] = p;
        rs += p;
      }
#pragma unroll
      for (int off = 1; off < 16; off <<= 1) rs += __shfl_xor(rs, off);
      lrun[jj] = lrun[jj] * sc + rs;
#pragma unroll
      for (int nd = 0; nd < 4; ++nd) acc_o[nd][jj] *= sc;
    }
    // P -> bf16 into wave-private LDS rows (swizzled)
#pragma unroll
    for (int n = 0; n < 4; ++n)
#pragma unroll
      for (int jj = 0; jj < 4; ++jj) {
        int pr = wv * 16 + ((lane >> 4) << 2) + jj;
        int pc = n * 16 + (lane & 15);
        pq[pr * 64 + (pc ^ ((pr & 7) << 3))] = __float2bfloat16(sv[n][jj]);
      }
    // O += P * V^T
    __builtin_amdgcn_s_setprio(1);
#pragma unroll
    for (int kk = 0; kk < 2; ++kk) {
      int c0 = kk * 32 + ((lane >> 4) << 3);
      bf16x8 pa, vf[4];
      {
        int r = wv * 16 + (lane & 15);
        pa = *(const bf16x8*)&pq[r * 64 + (c0 ^ ((r & 7) << 3))];
      }
#pragma unroll
      for (int nd = 0; nd < 4; ++nd) {
        int r = nd * 16 + (lane & 15);
        vf[nd] = *(const bf16x8*)&vs[cur][r * 64 + (c0 ^ ((r & 7) << 3))];
      }
#pragma unroll
      for (int nd = 0; nd < 4; ++nd) acc_o[nd] = mfma16(pa, vf[nd], acc_o[nd]);
    }
    __builtin_amdgcn_s_setprio(0);

    if (j + 1 < nkv) {
      LGKM0();
      VMC(0);
      BAR();
      cur ^= 1;
    }
  }
  // epilogue: O / l, scatter into attn (B*T, D) at head column h*64
  bf16* ob = attn + ((long)b * 512 + q0) * 1024 + h * 64;
#pragma unroll
  for (int jj = 0; jj < 4; ++jj) {
    float inv = 1.0f / lrun[jj];
    int r = wv * 16 + ((lane >> 4) << 2) + jj;
#pragma unroll
    for (int nd = 0; nd < 4; ++nd)
      ob[(long)r * 1024 + nd * 16 + (lane & 15)] = __float2bfloat16(acc_o[nd][jj] * inv);
  }
}

// ---------------------------------------------------------------------------
// LayerNorm over D=1024, one block per row. CONCAT: row from [memory|x].
// ---------------------------------------------------------------------------
template<bool CONCAT>
__global__ __launch_bounds__(256) void ln_kernel(
    const float* __restrict__ xin, const float* __restrict__ mem,
    const float* __restrict__ g, const float* __restrict__ beta,
    bf16* __restrict__ out)
{
  const int row = blockIdx.x;
  const float* src;
  if (CONCAT) {
    int b = row / 576, p = row % 576;
    src = (p < 64) ? (mem + ((long)b * 64 + p) * 1024)
                   : (xin + ((long)b * 512 + (p - 64)) * 1024);
  } else {
    src = xin + (long)row * 1024;
  }
  const int tid = threadIdx.x;
  float4 v = ((const float4*)src)[tid];
  float s = v.x + v.y + v.z + v.w;
  float s2 = v.x * v.x + v.y * v.y + v.z * v.z + v.w * v.w;
#pragma unroll
  for (int o = 32; o; o >>= 1) {
    s += __shfl_down(s, o);
    s2 += __shfl_down(s2, o);
  }
  __shared__ float red[8];
  const int w = tid >> 6, lane = tid & 63;
  if (lane == 0) { red[w] = s; red[4 + w] = s2; }
  __syncthreads();
  float S = red[0] + red[1] + red[2] + red[3];
  float S2 = red[4] + red[5] + red[6] + red[7];
  float mu = S * (1.0f / 1024.0f);
  float rs = rsqrtf(S2 * (1.0f / 1024.0f) - mu * mu + 1e-5f);
  float4 gg = ((const float4*)g)[tid];
  float4 bb = ((const float4*)beta)[tid];
  bf16x4s o4;
  o4.a = __float2bfloat16((v.x - mu) * rs * gg.x + bb.x);
  o4.b = __float2bfloat16((v.y - mu) * rs * gg.y + bb.y);
  o4.c = __float2bfloat16((v.z - mu) * rs * gg.z + bb.z);
  o4.d = __float2bfloat16((v.w - mu) * rs * gg.w + bb.w);
  *(bf16x4s*)(out + (long)row * 1024 + tid * 4) = o4;
}

// ---------------------------------------------------------------------------
// fp32 weights -> bf16, all 6 matrices packed [Wq|Wk|Wv|Wo|W1|W2]
// ---------------------------------------------------------------------------
__global__ __launch_bounds__(256) void cvt_weights(
    const float* __restrict__ wq, const float* __restrict__ wk,
    const float* __restrict__ wv, const float* __restrict__ wo,
    const float* __restrict__ w1, const float* __restrict__ w2,
    bf16* __restrict__ out)
{
  long e = ((long)blockIdx.x * 256 + threadIdx.x) * 4;
  const long DD = 1048576, DF = 4194304;
  const float* src; long base;
  if (e < DD)            { src = wq; base = 0; }
  else if (e < 2 * DD)   { src = wk; base = DD; }
  else if (e < 3 * DD)   { src = wv; base = 2 * DD; }
  else if (e < 4 * DD)   { src = wo; base = 3 * DD; }
  else if (e < 4 * DD + DF) { src = w1; base = 4 * DD; }
  else                   { src = w2; base = 4 * DD + DF; }
  float4 v = *(const float4*)(src + (e - base));
  bf16x4s o4;
  o4.a = __float2bfloat16(v.x);
  o4.b = __float2bfloat16(v.y);
  o4.c = __float2bfloat16(v.z);
  o4.d = __float2bfloat16(v.w);
  *(bf16x4s*)(out + e) = o4;
}

__global__ __launch_bounds__(256) void bias_concat(
    const float* __restrict__ bq, const float* __restrict__ bk,
    const float* __restrict__ bv, float* __restrict__ out)
{
  int i = blockIdx.x * 256 + threadIdx.x;
  if (i < 1024)      out[i] = bq[i];
  else if (i < 2048) out[i] = bk[i - 1024];
  else if (i < 3072) out[i] = bv[i - 2048];
}

// cos/sin table for RoPE: tab[p*16+f] = cos(p * 10000^(-f/16)), +9216 for sin
__global__ __launch_bounds__(256) void rope_tab_kernel(float* __restrict__ tab)
{
  int i = blockIdx.x * 256 + threadIdx.x;
  if (i >= 9216) return;
  int p = i >> 4, f = i & 15;
  float invf = expf(-(float)f * 0.5756462732485114f);  // 10000^(-f/16)
  float ang = (float)p * invf;
  tab[i] = cosf(ang);
  tab[9216 + i] = sinf(ang);
}

// ---------------------------------------------------------------------------
// RoPE + head-layout reshape. Q is pre-scaled by 0.125*log2(e) so the fused
// attention computes softmax in the exp2 domain.
// qkv: (B*L, 3072) bf16 -> qh (B,H,T,64) [rows p>=64], kh (B,H,L,64),
// vt (B,H,64,L) [transposed for PV B^T MFMA].
// ---------------------------------------------------------------------------
__global__ __launch_bounds__(256) void rope_reshape(
    const bf16* __restrict__ qkv, const float* __restrict__ tab,
    bf16* __restrict__ qh, bf16* __restrict__ kh, bf16* __restrict__ vt)
{
  const float QSCALE = 0.18033688011112043f;  // 0.125 * log2(e)
  long i = (long)blockIdx.x * 256 + threadIdx.x;
  if (i >= 8L * 576 * 1024) return;
  int dfull = (int)(i & 1023);
  long bp = i >> 10;
  int p = (int)(bp % 576);
  int b = (int)(bp / 576);
  int h = dfull >> 6, d = dfull & 63;
  const bf16* rowp = qkv + bp * 3072;

  float cosv = 1.0f, sinv = 0.0f;
  const bool rot = d < 32;
  int pd = 0;
  if (rot) {
    int i0 = d & 15;
    cosv = tab[p * 16 + i0];
    sinv = tab[9216 + p * 16 + i0];
    pd = (d < 16) ? d + 16 : d - 16;
  }
  // K (+RoPE)
  {
    float v0 = __bfloat162float(rowp[1024 + dfull]);
    float ov = v0;
    if (rot) {
      float v1 = __bfloat162float(rowp[1024 + (h << 6) + pd]);
      ov = (d < 16) ? (v0 * cosv - v1 * sinv) : (v0 * cosv + v1 * sinv);
    }
    kh[(((long)b * 16 + h) * 576 + p) * 64 + d] = __float2bfloat16(ov);
  }
  // V transpose
  vt[(((long)b * 16 + h) * 64 + d) * 576 + p] = rowp[2048 + dfull];
  // Q (+RoPE, + scale), only the T query rows
  if (p >= 64) {
    float v0 = __bfloat162float(rowp[dfull]);
    float ov = v0;
    if (rot) {
      float v1 = __bfloat162float(rowp[(h << 6) + pd]);
      ov = (d < 16) ? (v0 * cosv - v1 * sinv) : (v0 * cosv + v1 * sinv);
    }
    qh[(((long)b * 16 + h) * 512 + (p - 64)) * 64 + d] = __float2bfloat16(ov * QSCALE);
  }
}

// ---------------------------------------------------------------------------
extern "C" void kernel_launch(void* const* d_in, const int* in_sizes, int n_in,
                              void* d_out, int out_size, void* d_ws, size_t ws_size,
                              hipStream_t stream)
{
  (void)in_sizes; (void)n_in; (void)out_size; (void)ws_size;
  const float* x    = (const float*)d_in[0];
  const float* mem  = (const float*)d_in[1];
  const float* Wq   = (const float*)d_in[2];
  const float* bq   = (const float*)d_in[3];
  const float* Wk   = (const float*)d_in[4];
  const float* bk   = (const float*)d_in[5];
  const float* Wv   = (const float*)d_in[6];
  const float* bv   = (const float*)d_in[7];
  const float* Wo   = (const float*)d_in[8];
  const float* bo   = (const float*)d_in[9];
  const float* W1   = (const float*)d_in[10];
  const float* b1   = (const float*)d_in[11];
  const float* W2   = (const float*)d_in[12];
  const float* b2   = (const float*)d_in[13];
  const float* g_a  = (const float*)d_in[14];
  const float* bt_a = (const float*)d_in[15];
  const float* g_m  = (const float*)d_in[16];
  const float* bt_m = (const float*)d_in[17];
  float* out = (float*)d_out;

  char* ws = (char*)d_ws;
  size_t off = 0;
  auto carve = [&](size_t bytes) -> void* {
    void* p = ws + off;
    off = (off + bytes + 255) & ~(size_t)255;
    return p;
  };
  bf16*  wB    = (bf16*)carve(12582912L * 2);        // packed bf16 weights
  float* bqkv  = (float*)carve(3072 * 4);
  float* rtab  = (float*)carve(9216 * 2 * 4);        // rope cos/sin table
  bf16*  xa    = (bf16*)carve(4608L * 1024 * 2);     // LN1 out
  bf16*  qkv   = (bf16*)carve(4608L * 3072 * 2);     // QKV GEMM out
  bf16*  qh    = (bf16*)carve(8L * 16 * 512 * 64 * 2);
  bf16*  kh    = (bf16*)carve(8L * 16 * 576 * 64 * 2);
  bf16*  vt    = (bf16*)carve(8L * 16 * 576 * 64 * 2);
  bf16*  attn  = (bf16*)carve(4096L * 1024 * 2);     // flash out, (B*T, D)
  float* x2    = (float*)carve(4096L * 1024 * 4);    // post-attn residual
  bf16*  xn    = (bf16*)carve(4096L * 1024 * 2);     // LN2 out
  bf16*  hbuf  = (bf16*)carve(4096L * 4096 * 2);     // relu^2 hidden
  float* parts = (float*)carve(4L * 4096 * 1024 * 4);// split-K partials (67MB)

  cvt_weights<<<12288, 256, 0, stream>>>(Wq, Wk, Wv, Wo, W1, W2, wB);
  bias_concat<<<12, 256, 0, stream>>>(bq, bk, bv, bqkv);
  rope_tab_kernel<<<36, 256, 0, stream>>>(rtab);
  ln_kernel<true><<<4608, 256, 0, stream>>>(x, mem, g_a, bt_a, xa);

  // QKV: (4608,1024) x (3072,1024)^T -> (4608,3072)   grid (12,18) = 216
  gemm256<0><<<dim3(12, 18, 1), 512, 0, stream>>>(
      xa, 1024, 0, wB, 1024, 0, bqkv, qkv, 1024, 3072, 0);

  rope_reshape<<<18432, 256, 0, stream>>>(qkv, rtab, qh, kh, vt);

  // fused flash attention: 1024 blocks (8 q-tiles x 128 bh, XCD-permuted)
  flash_attn<<<1024, 256, 0, stream>>>(qh, kh, vt, attn);

  // Wo split-K=4: (4096,1024)x(1024,1024)^T, slice K=256 -> grid (4,16,4)=256
  gemm256<5><<<dim3(4, 16, 4), 512, 0, stream>>>(
      attn, 1024, 256, wB + 3145728L, 1024, 256, nullptr, parts, 256, 1024, 4194304L);
  // fused: x2 = sum(parts)+bo+x ; xn = LN(x2)
  reduce_ln<<<4096, 256, 0, stream>>>(parts, bo, x, g_m, bt_m, x2, xn);

  // W1 + relu^2: (4096,1024)x(4096,1024)^T -> (4096,4096) bf16, grid (16,16)
  gemm256<2><<<dim3(16, 16, 1), 512, 0, stream>>>(
      xn, 1024, 0, wB + 4194304L, 1024, 0, b1, hbuf, 1024, 4096, 0);

  // W2 split-K=4: (4096,4096)x(1024,4096)^T, slice K=1024 -> grid (4,16,4)=256
  gemm256<5><<<dim3(4, 16, 4), 512, 0, stream>>>(
      hbuf, 4096, 1024, wB + 8388608L, 4096, 1024, nullptr, parts, 1024, 1024, 4194304L);
  reduce_k<4><<<4096, 256, 0, stream>>>(parts, b2, x2, out, 256, 1048576);
}